// Round 1
// baseline (1145.163 us; speedup 1.0000x reference)
//
#include <hip/hip_runtime.h>

#define N0c 100000
#define N1c 25000
#define N2c 5000
#define E0c 400000
#define E1c 80000
// IN_FEATS = N_HIDDEN = 512, N_CLASSES = 64

// ---------------------------------------------------------------------------
// GEMM (NT): C[M,512] = A[M,512] @ B[512,512]^T, tile 128x128, micro 8x8
// EPI 0: C[m][n]        = relu(acc + bias[n]) - hist[m*512+n]          (ldc 512)
// EPI 1: C[m][n]        = (acc+bias[n]) - hist[m*1024+n]
//        C[m][512+n]    = relu(acc+bias[n]) - hist[m*1024+512+n]       (ldc 1024)
// ---------------------------------------------------------------------------
template<int EPI>
__global__ __launch_bounds__(256)
void gemm128(const float* __restrict__ A, const float* __restrict__ B,
             const float* __restrict__ bias, const float* __restrict__ hist,
             float* __restrict__ C, int M)
{
    const int K = 512;
    __shared__ float As[16][132];
    __shared__ float Bs[16][132];
    const int tid = threadIdx.x;
    const int tx = tid & 15, ty = tid >> 4;
    const int bm = blockIdx.x, bn = blockIdx.y;
    const int lrow = tid >> 2;        // 0..63
    const int lk   = (tid & 3) * 4;   // 0,4,8,12

    float acc[2][4][2][4];
    #pragma unroll
    for (int a = 0; a < 2; ++a)
        #pragma unroll
        for (int i = 0; i < 4; ++i)
            #pragma unroll
            for (int b = 0; b < 2; ++b)
                #pragma unroll
                for (int j = 0; j < 4; ++j) acc[a][i][b][j] = 0.f;

    int ar0 = bm * 128 + lrow;      if (ar0 > M - 1) ar0 = M - 1;
    int ar1 = bm * 128 + 64 + lrow; if (ar1 > M - 1) ar1 = M - 1;
    const int br0 = bn * 128 + lrow;   // < 512 always
    const int br1 = br0 + 64;

    const float* Ap0 = A + (size_t)ar0 * K + lk;
    const float* Ap1 = A + (size_t)ar1 * K + lk;
    const float* Bp0 = B + (size_t)br0 * K + lk;
    const float* Bp1 = B + (size_t)br1 * K + lk;

    for (int kt = 0; kt < K; kt += 16) {
        float4 a0 = *(const float4*)(Ap0 + kt);
        float4 a1 = *(const float4*)(Ap1 + kt);
        float4 b0 = *(const float4*)(Bp0 + kt);
        float4 b1 = *(const float4*)(Bp1 + kt);
        __syncthreads();
        As[lk+0][lrow]    = a0.x; As[lk+1][lrow]    = a0.y; As[lk+2][lrow]    = a0.z; As[lk+3][lrow]    = a0.w;
        As[lk+0][lrow+64] = a1.x; As[lk+1][lrow+64] = a1.y; As[lk+2][lrow+64] = a1.z; As[lk+3][lrow+64] = a1.w;
        Bs[lk+0][lrow]    = b0.x; Bs[lk+1][lrow]    = b0.y; Bs[lk+2][lrow]    = b0.z; Bs[lk+3][lrow]    = b0.w;
        Bs[lk+0][lrow+64] = b1.x; Bs[lk+1][lrow+64] = b1.y; Bs[lk+2][lrow+64] = b1.z; Bs[lk+3][lrow+64] = b1.w;
        __syncthreads();
        #pragma unroll
        for (int kk = 0; kk < 16; ++kk) {
            float4 av0 = *(const float4*)&As[kk][ty * 4];
            float4 av1 = *(const float4*)&As[kk][64 + ty * 4];
            float4 bv0 = *(const float4*)&Bs[kk][tx * 4];
            float4 bv1 = *(const float4*)&Bs[kk][64 + tx * 4];
            float aa[2][4] = {{av0.x, av0.y, av0.z, av0.w}, {av1.x, av1.y, av1.z, av1.w}};
            float bb[2][4] = {{bv0.x, bv0.y, bv0.z, bv0.w}, {bv1.x, bv1.y, bv1.z, bv1.w}};
            #pragma unroll
            for (int ci = 0; ci < 2; ++ci)
                #pragma unroll
                for (int i = 0; i < 4; ++i)
                    #pragma unroll
                    for (int cj = 0; cj < 2; ++cj)
                        #pragma unroll
                        for (int j = 0; j < 4; ++j)
                            acc[ci][i][cj][j] += aa[ci][i] * bb[cj][j];
        }
    }

    #pragma unroll
    for (int ci = 0; ci < 2; ++ci) {
        #pragma unroll
        for (int i = 0; i < 4; ++i) {
            const int m = bm * 128 + ci * 64 + ty * 4 + i;
            if (m >= M) continue;
            #pragma unroll
            for (int cj = 0; cj < 2; ++cj) {
                const int n = bn * 128 + cj * 64 + tx * 4;
                const float4 bv = *(const float4*)&bias[n];
                const float r0 = acc[ci][i][cj][0] + bv.x;
                const float r1 = acc[ci][i][cj][1] + bv.y;
                const float r2 = acc[ci][i][cj][2] + bv.z;
                const float r3 = acc[ci][i][cj][3] + bv.w;
                if (EPI == 0) {
                    const float4 hv = *(const float4*)&hist[(size_t)m * 512 + n];
                    float4 o;
                    o.x = fmaxf(r0, 0.f) - hv.x;
                    o.y = fmaxf(r1, 0.f) - hv.y;
                    o.z = fmaxf(r2, 0.f) - hv.z;
                    o.w = fmaxf(r3, 0.f) - hv.w;
                    *(float4*)&C[(size_t)m * 512 + n] = o;
                } else {
                    const float4 ha = *(const float4*)&hist[(size_t)m * 1024 + n];
                    const float4 hb = *(const float4*)&hist[(size_t)m * 1024 + 512 + n];
                    float4 o0, o1;
                    o0.x = r0 - ha.x; o0.y = r1 - ha.y; o0.z = r2 - ha.z; o0.w = r3 - ha.w;
                    o1.x = fmaxf(r0, 0.f) - hb.x;
                    o1.y = fmaxf(r1, 0.f) - hb.y;
                    o1.z = fmaxf(r2, 0.f) - hb.z;
                    o1.w = fmaxf(r3, 0.f) - hb.w;
                    *(float4*)&C[(size_t)m * 1024 + n]       = o0;
                    *(float4*)&C[(size_t)m * 1024 + 512 + n] = o1;
                }
            }
        }
    }
}

// ---------------------------------------------------------------------------
// Small GEMM: out[M,64] = A[M,1024] @ B[64,1024]^T + bias   (final classifier)
// ---------------------------------------------------------------------------
__global__ __launch_bounds__(256)
void gemm64(const float* __restrict__ A, const float* __restrict__ B,
            const float* __restrict__ bias, float* __restrict__ C, int M)
{
    const int K = 1024;
    __shared__ float As[32][68];
    __shared__ float Bs[32][68];
    const int tid = threadIdx.x;
    const int tx = tid & 15, ty = tid >> 4;
    const int lrow = tid >> 3;       // 0..31
    const int lk   = (tid & 7) * 4;  // 0..28
    const int bm = blockIdx.x;

    float acc[4][4];
    #pragma unroll
    for (int i = 0; i < 4; ++i)
        #pragma unroll
        for (int j = 0; j < 4; ++j) acc[i][j] = 0.f;

    int ar0 = bm * 64 + lrow;      if (ar0 > M - 1) ar0 = M - 1;
    int ar1 = bm * 64 + 32 + lrow; if (ar1 > M - 1) ar1 = M - 1;

    for (int kt = 0; kt < K; kt += 32) {
        float4 a0 = *(const float4*)(A + (size_t)ar0 * K + kt + lk);
        float4 a1 = *(const float4*)(A + (size_t)ar1 * K + kt + lk);
        float4 b0 = *(const float4*)(B + (size_t)lrow * K + kt + lk);
        float4 b1 = *(const float4*)(B + (size_t)(32 + lrow) * K + kt + lk);
        __syncthreads();
        As[lk+0][lrow]    = a0.x; As[lk+1][lrow]    = a0.y; As[lk+2][lrow]    = a0.z; As[lk+3][lrow]    = a0.w;
        As[lk+0][lrow+32] = a1.x; As[lk+1][lrow+32] = a1.y; As[lk+2][lrow+32] = a1.z; As[lk+3][lrow+32] = a1.w;
        Bs[lk+0][lrow]    = b0.x; Bs[lk+1][lrow]    = b0.y; Bs[lk+2][lrow]    = b0.z; Bs[lk+3][lrow]    = b0.w;
        Bs[lk+0][lrow+32] = b1.x; Bs[lk+1][lrow+32] = b1.y; Bs[lk+2][lrow+32] = b1.z; Bs[lk+3][lrow+32] = b1.w;
        __syncthreads();
        #pragma unroll
        for (int kk = 0; kk < 32; ++kk) {
            float4 av = *(const float4*)&As[kk][ty * 4];
            float4 bv = *(const float4*)&Bs[kk][tx * 4];
            float aa[4] = {av.x, av.y, av.z, av.w};
            float bb[4] = {bv.x, bv.y, bv.z, bv.w};
            #pragma unroll
            for (int i = 0; i < 4; ++i)
                #pragma unroll
                for (int j = 0; j < 4; ++j)
                    acc[i][j] += aa[i] * bb[j];
        }
    }

    const float4 bv = *(const float4*)&bias[tx * 4];
    #pragma unroll
    for (int i = 0; i < 4; ++i) {
        const int m = bm * 64 + ty * 4 + i;
        if (m >= M) continue;
        float4 o;
        o.x = acc[i][0] + bv.x; o.y = acc[i][1] + bv.y;
        o.z = acc[i][2] + bv.z; o.w = acc[i][3] + bv.w;
        *(float4*)&C[(size_t)m * 64 + tx * 4] = o;
    }
}

// ---------------------------------------------------------------------------
// CSR build: degree count -> exclusive scan -> edge scatter
// ---------------------------------------------------------------------------
__global__ void count_deg(const int* __restrict__ dst, int* __restrict__ deg, int E)
{
    int e = blockIdx.x * blockDim.x + threadIdx.x;
    if (e < E) atomicAdd(&deg[dst[e]], 1);
}

__global__ __launch_bounds__(1024)
void exscan(const int* __restrict__ deg, int* __restrict__ off, int* __restrict__ cur, int n)
{
    __shared__ int wsum[16];
    __shared__ int carry;
    const int tid = threadIdx.x, lane = tid & 63, w = tid >> 6;
    if (tid == 0) carry = 0;
    __syncthreads();
    for (int base = 0; base < n; base += 1024) {
        const int i = base + tid;
        const int v = (i < n) ? deg[i] : 0;
        int x = v;
        #pragma unroll
        for (int d = 1; d < 64; d <<= 1) {
            int y = __shfl_up(x, d, 64);
            if (lane >= d) x += y;
        }
        if (lane == 63) wsum[w] = x;
        __syncthreads();
        int wo = 0, tot = 0;
        #pragma unroll
        for (int k = 0; k < 16; ++k) { int s = wsum[k]; tot += s; if (k < w) wo += s; }
        const int excl = carry + wo + x - v;
        if (i < n) { off[i] = excl; cur[i] = excl; }
        __syncthreads();
        if (tid == 0) carry += tot;
        __syncthreads();
    }
    if (tid == 0) off[n] = carry;
}

__global__ void scatter_edges(const int* __restrict__ src, const int* __restrict__ dst,
                              int* __restrict__ cur, int* __restrict__ eidx, int E)
{
    int e = blockIdx.x * blockDim.x + threadIdx.x;
    if (e < E) {
        int p = atomicAdd(&cur[dst[e]], 1);
        eidx[p] = src[e];
    }
}

// ---------------------------------------------------------------------------
// Segment mean + residual add: out[d] = mean_{e in CSR[d]} h[eidx[e]] + addin[d]
// one wave per destination node; NV4 = float4s per lane (2 -> D=512, 4 -> D=1024)
// ---------------------------------------------------------------------------
template<int NV4>
__global__ __launch_bounds__(256)
void seg_mean_add(const float* __restrict__ h, const int* __restrict__ off,
                  const int* __restrict__ eidx, const float* __restrict__ addin,
                  float* __restrict__ out, int n_dst)
{
    const int D = NV4 * 256;
    const int wid = blockIdx.x * 4 + (threadIdx.x >> 6);
    const int lane = threadIdx.x & 63;
    if (wid >= n_dst) return;
    const int e0 = off[wid], e1 = off[wid + 1];
    float4 acc[NV4];
    #pragma unroll
    for (int j = 0; j < NV4; ++j) acc[j] = make_float4(0.f, 0.f, 0.f, 0.f);
    for (int e = e0; e < e1; ++e) {
        const float4* row = (const float4*)(h + (size_t)eidx[e] * D);
        #pragma unroll
        for (int j = 0; j < NV4; ++j) {
            float4 v = row[lane + 64 * j];
            acc[j].x += v.x; acc[j].y += v.y; acc[j].z += v.z; acc[j].w += v.w;
        }
    }
    const float s = 1.0f / (float)((e1 - e0) > 0 ? (e1 - e0) : 1);
    const float4* ad = (const float4*)(addin + (size_t)wid * D);
    float4* o = (float4*)(out + (size_t)wid * D);
    #pragma unroll
    for (int j = 0; j < NV4; ++j) {
        float4 a = ad[lane + 64 * j];
        float4 r;
        r.x = acc[j].x * s + a.x; r.y = acc[j].y * s + a.y;
        r.z = acc[j].z * s + a.z; r.w = acc[j].w * s + a.w;
        o[lane + 64 * j] = r;
    }
}

// ---------------------------------------------------------------------------
extern "C" void kernel_launch(void* const* d_in, const int* in_sizes, int n_in,
                              void* d_out, int out_size, void* d_ws, size_t ws_size,
                              hipStream_t stream)
{
    const float* feats   = (const float*)d_in[0];
    const float* h0_hist = (const float*)d_in[1];
    const float* agg_h0  = (const float*)d_in[2];
    const float* h1_hist = (const float*)d_in[3];
    const float* agg_h1  = (const float*)d_in[4];
    const float* W0 = (const float*)d_in[5];
    const float* b0 = (const float*)d_in[6];
    const float* W1 = (const float*)d_in[7];
    const float* b1 = (const float*)d_in[8];
    const float* W2 = (const float*)d_in[9];
    const float* b2 = (const float*)d_in[10];
    const int* src0 = (const int*)d_in[11];
    const int* dst0 = (const int*)d_in[12];
    const int* src1 = (const int*)d_in[13];
    const int* dst1 = (const int*)d_in[14];

    char* ws = (char*)d_ws;
    float* h0    = (float*)(ws);                                   // N0*512 f32 (reused as h1cat N1*1024)
    float* agg0  = (float*)(ws + (size_t)N0c * 512 * 4);           // N1*512
    float* agg1  = (float*)(ws + (size_t)N0c * 512 * 4 + (size_t)N1c * 512 * 4);  // N2*1024
    char*  ip    = ws + (size_t)N0c * 512 * 4 + (size_t)N1c * 512 * 4 + (size_t)N2c * 1024 * 4;
    int* deg0  = (int*)ip; ip += sizeof(int) * N1c;
    int* off0  = (int*)ip; ip += sizeof(int) * (N1c + 1);
    int* cur0  = (int*)ip; ip += sizeof(int) * N1c;
    int* eidx0 = (int*)ip; ip += sizeof(int) * E0c;
    int* deg1  = (int*)ip; ip += sizeof(int) * N2c;
    int* off1  = (int*)ip; ip += sizeof(int) * (N2c + 1);
    int* cur1  = (int*)ip; ip += sizeof(int) * N2c;
    int* eidx1 = (int*)ip; ip += sizeof(int) * E1c;
    float* h1cat = h0;

    hipMemsetAsync(deg0, 0, sizeof(int) * N1c, stream);
    hipMemsetAsync(deg1, 0, sizeof(int) * N2c, stream);

    // layer 0: h0 = relu(feats @ W0^T + b0) - h0_hist
    gemm128<0><<<dim3((N0c + 127) / 128, 4), 256, 0, stream>>>(feats, W0, b0, h0_hist, h0, N0c);

    // CSR for level-0 edges, then agg0 = segment_mean(h0) + agg_h0
    count_deg<<<(E0c + 255) / 256, 256, 0, stream>>>(dst0, deg0, E0c);
    exscan<<<1, 1024, 0, stream>>>(deg0, off0, cur0, N1c);
    scatter_edges<<<(E0c + 255) / 256, 256, 0, stream>>>(src0, dst0, cur0, eidx0, E0c);
    seg_mean_add<2><<<(N1c + 3) / 4, 256, 0, stream>>>(h0, off0, eidx0, agg_h0, agg0, N1c);

    // layer 1: h1cat = concat(h1, relu(h1)) - h1_hist, h1 = agg0 @ W1^T + b1
    gemm128<1><<<dim3((N1c + 127) / 128, 4), 256, 0, stream>>>(agg0, W1, b1, h1_hist, h1cat, N1c);

    // CSR for level-1 edges, then agg1 = segment_mean(h1cat) + agg_h1
    count_deg<<<(E1c + 255) / 256, 256, 0, stream>>>(dst1, deg1, E1c);
    exscan<<<1, 1024, 0, stream>>>(deg1, off1, cur1, N2c);
    scatter_edges<<<(E1c + 255) / 256, 256, 0, stream>>>(src1, dst1, cur1, eidx1, E1c);
    seg_mean_add<4><<<(N2c + 3) / 4, 256, 0, stream>>>(h1cat, off1, eidx1, agg_h1, agg1, N2c);

    // classifier: out = agg1 @ W2^T + b2
    gemm64<<<(N2c + 63) / 64, 256, 0, stream>>>(agg1, W2, b2, (float*)d_out, N2c);
}

// Round 2
// 860.946 us; speedup vs baseline: 1.3301x; 1.3301x over previous
//
#include <hip/hip_runtime.h>

#define N0c 100000
#define N1c 25000
#define N2c 5000
#define E0c 400000
#define E1c 80000
// IN_FEATS = N_HIDDEN = 512, N_CLASSES = 64

typedef __attribute__((ext_vector_type(8))) short bf16x8;
typedef __attribute__((ext_vector_type(4))) float f32x4;

// round-to-nearest-even bf16, returned as fp32 bit pattern (low 16 zeroed)
static __device__ __forceinline__ uint rnd_bf(float f) {
    uint u = __float_as_uint(f);
    return (u + 0x7FFFu + ((u >> 16) & 1u)) & 0xFFFF0000u;
}

// split 8 floats into hi-bf16 octet and lo-bf16 octet (packed, k-ascending)
static __device__ __forceinline__ void split8(float4 p0, float4 p1, uint4& hi, uint4& lo) {
    float f[8] = {p0.x, p0.y, p0.z, p0.w, p1.x, p1.y, p1.z, p1.w};
    uint h[8];
    float lf[8];
#pragma unroll
    for (int i = 0; i < 8; ++i) {
        h[i] = rnd_bf(f[i]);
        lf[i] = f[i] - __uint_as_float(h[i]);
    }
    hi.x = (h[0] >> 16) | h[1]; hi.y = (h[2] >> 16) | h[3];
    hi.z = (h[4] >> 16) | h[5]; hi.w = (h[6] >> 16) | h[7];
    uint g[8];
#pragma unroll
    for (int i = 0; i < 8; ++i) g[i] = rnd_bf(lf[i]);
    lo.x = (g[0] >> 16) | g[1]; lo.y = (g[2] >> 16) | g[3];
    lo.z = (g[4] >> 16) | g[5]; lo.w = (g[6] >> 16) | g[7];
}

// ---------------------------------------------------------------------------
// bf16x2 split-precision MFMA GEMM (NT): C[M,512] = A[M,512] @ B[512,512]^T
// tile 128x128, 4 waves (2x2), each wave 64x64 = 4x4 frags of 16x16x32.
// EPI 0: C[m][n]     = relu(acc+bias[n]) - hist[m*512+n]           (ldc 512)
// EPI 1: C[m][n]     = (acc+bias[n]) - hist[m*1024+n]
//        C[m][512+n] = relu(acc+bias[n]) - hist[m*1024+512+n]      (ldc 1024)
// LDS per tile row: 8 x 16B slots (hi octets g=0..3, lo octets 4..7),
// physical slot = logical ^ (row & 7)  (bank-conflict swizzle).
// ---------------------------------------------------------------------------
template<int EPI>
__global__ __launch_bounds__(256, 2)
void gemm_mfma(const float* __restrict__ A, const float* __restrict__ B,
               const float* __restrict__ bias, const float* __restrict__ hist,
               float* __restrict__ C, int M, int nblk)
{
    __shared__ uint4 lds[2048];  // A: [0,1024), B: [1024,2048)  (32 KiB)

    const int tid = threadIdx.x;
    // XCD-aware bijective swizzle (nblk % 8 == 0 guaranteed by launch)
    const int phys = blockIdx.x;
    const int lid = (phys & 7) * (nblk >> 3) + (phys >> 3);
    const int bm = lid >> 2, bn = lid & 3;

    const int w = tid >> 6, l = tid & 63;
    const int wm = w >> 1, wn = w & 1;
    const int lg = l >> 4, lr = l & 15;

    const int srow = tid >> 1;      // staging row 0..127
    const int shalf = tid & 1;      // which 16-float half of BK=32

    int arow = bm * 128 + srow; if (arow > M - 1) arow = M - 1;
    const float* Ap = A + (size_t)arow * 512 + shalf * 16;
    const float* Bp = B + (size_t)(bn * 128 + srow) * 512 + shalf * 16;

    f32x4 acc[4][4];
#pragma unroll
    for (int i = 0; i < 4; ++i)
#pragma unroll
        for (int j = 0; j < 4; ++j) acc[i][j] = {0.f, 0.f, 0.f, 0.f};

    float4 ar[4], br[4];
#pragma unroll
    for (int j = 0; j < 4; ++j) {
        ar[j] = *(const float4*)(Ap + j * 4);
        br[j] = *(const float4*)(Bp + j * 4);
    }

    const int g0 = shalf * 2;
    const int swW = srow & 7;
    const int wbaseA = srow * 8;
    const int wbaseB = 1024 + srow * 8;

    for (int kt = 0; kt < 16; ++kt) {
        __syncthreads();
        {
            uint4 h0, l0, h1, l1;
            split8(ar[0], ar[1], h0, l0);
            split8(ar[2], ar[3], h1, l1);
            lds[wbaseA + ((g0    ) ^ swW)] = h0;
            lds[wbaseA + ((g0 + 1) ^ swW)] = h1;
            lds[wbaseA + ((g0 + 4) ^ swW)] = l0;
            lds[wbaseA + ((g0 + 5) ^ swW)] = l1;
            split8(br[0], br[1], h0, l0);
            split8(br[2], br[3], h1, l1);
            lds[wbaseB + ((g0    ) ^ swW)] = h0;
            lds[wbaseB + ((g0 + 1) ^ swW)] = h1;
            lds[wbaseB + ((g0 + 4) ^ swW)] = l0;
            lds[wbaseB + ((g0 + 5) ^ swW)] = l1;
        }
        __syncthreads();
        if (kt < 15) {
#pragma unroll
            for (int j = 0; j < 4; ++j) {
                ar[j] = *(const float4*)(Ap + (kt + 1) * 32 + j * 4);
                br[j] = *(const float4*)(Bp + (kt + 1) * 32 + j * 4);
            }
        }
        bf16x8 ah[4], al[4], bh[4], bl[4];
#pragma unroll
        for (int mi = 0; mi < 4; ++mi) {
            const int r = wm * 64 + mi * 16 + lr;
            const int sw = r & 7;
            ah[mi] = *(const bf16x8*)&lds[r * 8 + ((lg    ) ^ sw)];
            al[mi] = *(const bf16x8*)&lds[r * 8 + ((lg + 4) ^ sw)];
        }
#pragma unroll
        for (int ni = 0; ni < 4; ++ni) {
            const int r = wn * 64 + ni * 16 + lr;
            const int sw = r & 7;
            bh[ni] = *(const bf16x8*)&lds[1024 + r * 8 + ((lg    ) ^ sw)];
            bl[ni] = *(const bf16x8*)&lds[1024 + r * 8 + ((lg + 4) ^ sw)];
        }
#pragma unroll
        for (int mi = 0; mi < 4; ++mi)
#pragma unroll
            for (int ni = 0; ni < 4; ++ni) {
                f32x4 c = acc[mi][ni];
                c = __builtin_amdgcn_mfma_f32_16x16x32_bf16(ah[mi], bh[ni], c, 0, 0, 0);
                c = __builtin_amdgcn_mfma_f32_16x16x32_bf16(ah[mi], bl[ni], c, 0, 0, 0);
                c = __builtin_amdgcn_mfma_f32_16x16x32_bf16(al[mi], bh[ni], c, 0, 0, 0);
                acc[mi][ni] = c;
            }
    }

#pragma unroll
    for (int mi = 0; mi < 4; ++mi)
#pragma unroll
        for (int ni = 0; ni < 4; ++ni) {
            const int col = bn * 128 + wn * 64 + ni * 16 + lr;
            const float bv = bias[col];
#pragma unroll
            for (int r = 0; r < 4; ++r) {
                const int m = bm * 128 + wm * 64 + mi * 16 + lg * 4 + r;
                if (m < M) {
                    const float v = acc[mi][ni][r] + bv;
                    if (EPI == 0) {
                        C[(size_t)m * 512 + col] = fmaxf(v, 0.f) - hist[(size_t)m * 512 + col];
                    } else {
                        C[(size_t)m * 1024 + col]       = v - hist[(size_t)m * 1024 + col];
                        C[(size_t)m * 1024 + 512 + col] = fmaxf(v, 0.f) - hist[(size_t)m * 1024 + 512 + col];
                    }
                }
            }
        }
}

// ---------------------------------------------------------------------------
// Small GEMM: out[M,64] = A[M,1024] @ B[64,1024]^T + bias   (final classifier)
// ---------------------------------------------------------------------------
__global__ __launch_bounds__(256)
void gemm64(const float* __restrict__ A, const float* __restrict__ B,
            const float* __restrict__ bias, float* __restrict__ C, int M)
{
    const int K = 1024;
    __shared__ float As[32][68];
    __shared__ float Bs[32][68];
    const int tid = threadIdx.x;
    const int tx = tid & 15, ty = tid >> 4;
    const int lrow = tid >> 3;
    const int lk   = (tid & 7) * 4;
    const int bm = blockIdx.x;

    float acc[4][4];
#pragma unroll
    for (int i = 0; i < 4; ++i)
#pragma unroll
        for (int j = 0; j < 4; ++j) acc[i][j] = 0.f;

    int ar0 = bm * 64 + lrow;      if (ar0 > M - 1) ar0 = M - 1;
    int ar1 = bm * 64 + 32 + lrow; if (ar1 > M - 1) ar1 = M - 1;

    for (int kt = 0; kt < K; kt += 32) {
        float4 a0 = *(const float4*)(A + (size_t)ar0 * K + kt + lk);
        float4 a1 = *(const float4*)(A + (size_t)ar1 * K + kt + lk);
        float4 b0 = *(const float4*)(B + (size_t)lrow * K + kt + lk);
        float4 b1 = *(const float4*)(B + (size_t)(32 + lrow) * K + kt + lk);
        __syncthreads();
        As[lk+0][lrow]    = a0.x; As[lk+1][lrow]    = a0.y; As[lk+2][lrow]    = a0.z; As[lk+3][lrow]    = a0.w;
        As[lk+0][lrow+32] = a1.x; As[lk+1][lrow+32] = a1.y; As[lk+2][lrow+32] = a1.z; As[lk+3][lrow+32] = a1.w;
        Bs[lk+0][lrow]    = b0.x; Bs[lk+1][lrow]    = b0.y; Bs[lk+2][lrow]    = b0.z; Bs[lk+3][lrow]    = b0.w;
        Bs[lk+0][lrow+32] = b1.x; Bs[lk+1][lrow+32] = b1.y; Bs[lk+2][lrow+32] = b1.z; Bs[lk+3][lrow+32] = b1.w;
        __syncthreads();
#pragma unroll
        for (int kk = 0; kk < 32; ++kk) {
            float4 av = *(const float4*)&As[kk][ty * 4];
            float4 bv = *(const float4*)&Bs[kk][tx * 4];
            float aa[4] = {av.x, av.y, av.z, av.w};
            float bb[4] = {bv.x, bv.y, bv.z, bv.w};
#pragma unroll
            for (int i = 0; i < 4; ++i)
#pragma unroll
                for (int j = 0; j < 4; ++j)
                    acc[i][j] += aa[i] * bb[j];
        }
    }

    const float4 bv = *(const float4*)&bias[tx * 4];
#pragma unroll
    for (int i = 0; i < 4; ++i) {
        const int m = bm * 64 + ty * 4 + i;
        if (m >= M) continue;
        float4 o;
        o.x = acc[i][0] + bv.x; o.y = acc[i][1] + bv.y;
        o.z = acc[i][2] + bv.z; o.w = acc[i][3] + bv.w;
        *(float4*)&C[(size_t)m * 64 + tx * 4] = o;
    }
}

// ---------------------------------------------------------------------------
// CSR build: degree count -> exclusive scan -> edge scatter
// ---------------------------------------------------------------------------
__global__ void count_deg(const int* __restrict__ dst, int* __restrict__ deg, int E)
{
    int e = blockIdx.x * blockDim.x + threadIdx.x;
    if (e < E) atomicAdd(&deg[dst[e]], 1);
}

__global__ __launch_bounds__(1024)
void exscan(const int* __restrict__ deg, int* __restrict__ off, int* __restrict__ cur, int n)
{
    __shared__ int wsum[16];
    __shared__ int carry;
    const int tid = threadIdx.x, lane = tid & 63, w = tid >> 6;
    if (tid == 0) carry = 0;
    __syncthreads();
    for (int base = 0; base < n; base += 1024) {
        const int i = base + tid;
        const int v = (i < n) ? deg[i] : 0;
        int x = v;
#pragma unroll
        for (int d = 1; d < 64; d <<= 1) {
            int y = __shfl_up(x, d, 64);
            if (lane >= d) x += y;
        }
        if (lane == 63) wsum[w] = x;
        __syncthreads();
        int wo = 0, tot = 0;
#pragma unroll
        for (int k = 0; k < 16; ++k) { int s = wsum[k]; tot += s; if (k < w) wo += s; }
        const int excl = carry + wo + x - v;
        if (i < n) { off[i] = excl; cur[i] = excl; }
        __syncthreads();
        if (tid == 0) carry += tot;
        __syncthreads();
    }
    if (tid == 0) off[n] = carry;
}

__global__ void scatter_edges(const int* __restrict__ src, const int* __restrict__ dst,
                              int* __restrict__ cur, int* __restrict__ eidx, int E)
{
    int e = blockIdx.x * blockDim.x + threadIdx.x;
    if (e < E) {
        int p = atomicAdd(&cur[dst[e]], 1);
        eidx[p] = src[e];
    }
}

// ---------------------------------------------------------------------------
// Segment mean + residual add: out[d] = mean_{e in CSR[d]} h[eidx[e]] + addin[d]
// ---------------------------------------------------------------------------
template<int NV4>
__global__ __launch_bounds__(256)
void seg_mean_add(const float* __restrict__ h, const int* __restrict__ off,
                  const int* __restrict__ eidx, const float* __restrict__ addin,
                  float* __restrict__ out, int n_dst)
{
    const int D = NV4 * 256;
    const int wid = blockIdx.x * 4 + (threadIdx.x >> 6);
    const int lane = threadIdx.x & 63;
    if (wid >= n_dst) return;
    const int e0 = off[wid], e1 = off[wid + 1];
    float4 acc[NV4];
#pragma unroll
    for (int j = 0; j < NV4; ++j) acc[j] = make_float4(0.f, 0.f, 0.f, 0.f);
    for (int e = e0; e < e1; ++e) {
        const float4* row = (const float4*)(h + (size_t)eidx[e] * D);
#pragma unroll
        for (int j = 0; j < NV4; ++j) {
            float4 v = row[lane + 64 * j];
            acc[j].x += v.x; acc[j].y += v.y; acc[j].z += v.z; acc[j].w += v.w;
        }
    }
    const float s = 1.0f / (float)((e1 - e0) > 0 ? (e1 - e0) : 1);
    const float4* ad = (const float4*)(addin + (size_t)wid * D);
    float4* o = (float4*)(out + (size_t)wid * D);
#pragma unroll
    for (int j = 0; j < NV4; ++j) {
        float4 a = ad[lane + 64 * j];
        float4 r;
        r.x = acc[j].x * s + a.x; r.y = acc[j].y * s + a.y;
        r.z = acc[j].z * s + a.z; r.w = acc[j].w * s + a.w;
        o[lane + 64 * j] = r;
    }
}

// ---------------------------------------------------------------------------
extern "C" void kernel_launch(void* const* d_in, const int* in_sizes, int n_in,
                              void* d_out, int out_size, void* d_ws, size_t ws_size,
                              hipStream_t stream)
{
    const float* feats   = (const float*)d_in[0];
    const float* h0_hist = (const float*)d_in[1];
    const float* agg_h0  = (const float*)d_in[2];
    const float* h1_hist = (const float*)d_in[3];
    const float* agg_h1  = (const float*)d_in[4];
    const float* W0 = (const float*)d_in[5];
    const float* b0 = (const float*)d_in[6];
    const float* W1 = (const float*)d_in[7];
    const float* b1 = (const float*)d_in[8];
    const float* W2 = (const float*)d_in[9];
    const float* b2 = (const float*)d_in[10];
    const int* src0 = (const int*)d_in[11];
    const int* dst0 = (const int*)d_in[12];
    const int* src1 = (const int*)d_in[13];
    const int* dst1 = (const int*)d_in[14];

    char* ws = (char*)d_ws;
    float* h0    = (float*)(ws);                                   // N0*512 f32 (reused as h1cat N1*1024)
    float* agg0  = (float*)(ws + (size_t)N0c * 512 * 4);           // N1*512
    float* agg1  = (float*)(ws + (size_t)N0c * 512 * 4 + (size_t)N1c * 512 * 4);  // N2*1024
    char*  ip    = ws + (size_t)N0c * 512 * 4 + (size_t)N1c * 512 * 4 + (size_t)N2c * 1024 * 4;
    int* deg0  = (int*)ip; ip += sizeof(int) * N1c;
    int* off0  = (int*)ip; ip += sizeof(int) * (N1c + 1);
    int* cur0  = (int*)ip; ip += sizeof(int) * N1c;
    int* eidx0 = (int*)ip; ip += sizeof(int) * E0c;
    int* deg1  = (int*)ip; ip += sizeof(int) * N2c;
    int* off1  = (int*)ip; ip += sizeof(int) * (N2c + 1);
    int* cur1  = (int*)ip; ip += sizeof(int) * N2c;
    int* eidx1 = (int*)ip; ip += sizeof(int) * E1c;
    float* h1cat = h0;

    hipMemsetAsync(deg0, 0, sizeof(int) * N1c, stream);
    hipMemsetAsync(deg1, 0, sizeof(int) * N2c, stream);

    // layer 0: h0 = relu(feats @ W0^T + b0) - h0_hist
    const int nblk0 = ((N0c + 127) / 128) * 4;   // 3128, %8==0
    gemm_mfma<0><<<nblk0, 256, 0, stream>>>(feats, W0, b0, h0_hist, h0, N0c, nblk0);

    // CSR for level-0 edges, then agg0 = segment_mean(h0) + agg_h0
    count_deg<<<(E0c + 255) / 256, 256, 0, stream>>>(dst0, deg0, E0c);
    exscan<<<1, 1024, 0, stream>>>(deg0, off0, cur0, N1c);
    scatter_edges<<<(E0c + 255) / 256, 256, 0, stream>>>(src0, dst0, cur0, eidx0, E0c);
    seg_mean_add<2><<<(N1c + 3) / 4, 256, 0, stream>>>(h0, off0, eidx0, agg_h0, agg0, N1c);

    // layer 1: h1cat = concat(h1, relu(h1)) - h1_hist, h1 = agg0 @ W1^T + b1
    const int nblk1 = ((N1c + 127) / 128) * 4;   // 784, %8==0
    gemm_mfma<1><<<nblk1, 256, 0, stream>>>(agg0, W1, b1, h1_hist, h1cat, N1c, nblk1);

    // CSR for level-1 edges, then agg1 = segment_mean(h1cat) + agg_h1
    count_deg<<<(E1c + 255) / 256, 256, 0, stream>>>(dst1, deg1, E1c);
    exscan<<<1, 1024, 0, stream>>>(deg1, off1, cur1, N2c);
    scatter_edges<<<(E1c + 255) / 256, 256, 0, stream>>>(src1, dst1, cur1, eidx1, E1c);
    seg_mean_add<4><<<(N2c + 3) / 4, 256, 0, stream>>>(h1cat, off1, eidx1, agg_h1, agg1, N2c);

    // classifier: out = agg1 @ W2^T + b2
    gemm64<<<(N2c + 63) / 64, 256, 0, stream>>>(agg1, W2, b2, (float*)d_out, N2c);
}

// Round 3
// 776.002 us; speedup vs baseline: 1.4757x; 1.1095x over previous
//
#include <hip/hip_runtime.h>

#define N0c 100000
#define N1c 25000
#define N2c 5000
#define E0c 400000
#define E1c 80000
// IN_FEATS = N_HIDDEN = 512, N_CLASSES = 64
// M-tiles: GEMM1 782 (pad 100096), GEMM2 196 (pad 25088)

typedef __attribute__((ext_vector_type(8))) short bf16x8;
typedef __attribute__((ext_vector_type(4))) float f32x4;

#define GLOAD_LDS(g, l) \
    __builtin_amdgcn_global_load_lds((__attribute__((address_space(1))) const unsigned int*)(const void*)(g), \
                                     (__attribute__((address_space(3))) unsigned int*)(void*)(l), 16, 0, 0)

// round-to-nearest-even bf16, returned as fp32 bit pattern (low 16 zeroed)
static __device__ __forceinline__ uint rnd_bf(float f) {
    uint u = __float_as_uint(f);
    return (u + 0x7FFFu + ((u >> 16) & 1u)) & 0xFFFF0000u;
}

// split 8 floats into hi-bf16 octet and lo-bf16 octet (packed, k-ascending)
static __device__ __forceinline__ void split8(float4 p0, float4 p1, uint4& hi, uint4& lo) {
    float f[8] = {p0.x, p0.y, p0.z, p0.w, p1.x, p1.y, p1.z, p1.w};
    uint h[8];
    float lf[8];
#pragma unroll
    for (int i = 0; i < 8; ++i) {
        h[i] = rnd_bf(f[i]);
        lf[i] = f[i] - __uint_as_float(h[i]);
    }
    hi.x = (h[0] >> 16) | h[1]; hi.y = (h[2] >> 16) | h[3];
    hi.z = (h[4] >> 16) | h[5]; hi.w = (h[6] >> 16) | h[7];
    uint g[8];
#pragma unroll
    for (int i = 0; i < 8; ++i) g[i] = rnd_bf(lf[i]);
    lo.x = (g[0] >> 16) | g[1]; lo.y = (g[2] >> 16) | g[3];
    lo.z = (g[4] >> 16) | g[5]; lo.w = (g[6] >> 16) | g[7];
}

// ---------------------------------------------------------------------------
// Pre-split: X[M][512] fp32 -> tiled split-bf16 planes.
// Tile = 128 rows x 32 k, stored as [r=128][p=8 slots x 16B] where
// physical slot p holds logical octet o = p ^ (r&7); o<4: hi k-octet o,
// o>=4: lo k-octet (o-4). Buffer: [mtile_local*16 + kt][1024 uint4].
// Rows >= M are zeroed. One octet per thread; writes perfectly linear.
// ---------------------------------------------------------------------------
__global__ __launch_bounds__(256)
void presplit(const float* __restrict__ X, uint4* __restrict__ out,
              int M, int tile0, int ntiles)
{
    const int id = blockIdx.x * 256 + threadIdx.x;
    const int slot = id & 1023;
    const int tk = id >> 10;               // mtl*16 + kt
    if (tk >= ntiles * 16) return;
    const int kt = tk & 15;
    const int mtl = tk >> 4;
    const int r = slot >> 3, p = slot & 7;
    const int o = p ^ (r & 7);
    const int row = (tile0 + mtl) * 128 + r;
    uint4 v = {0u, 0u, 0u, 0u};
    if (row < M) {
        const float* src = X + (size_t)row * 512 + kt * 32 + (o & 3) * 8;
        float4 x0 = *(const float4*)src;
        float4 x1 = *(const float4*)(src + 4);
        uint4 hi, lo;
        split8(x0, x1, hi, lo);
        v = (o < 4) ? hi : lo;
    }
    out[(size_t)tk * 1024 + slot] = v;
}

// ---------------------------------------------------------------------------
// bf16x2 split MFMA GEMM (NT): C[M,512] = A[M,512] @ B[512,512]^T
// A,B pre-split tiled buffers. 128x128 tile, 4 waves (2x2), BK=32,
// global_load_lds width-16 staging (layout identical in global and LDS),
// ds_read_b128 fragments (XOR swizzle -> 2-way bank alias = free),
// 3 MFMA per fragment pair (hi*hi + hi*lo + lo*hi).
// EPI 0: C[m][n]     = relu(acc+bias[n]) - hist[m*512+n]        (ldc 512)
// EPI 1: C[m][n]     = (acc+bias[n]) - hist[m*1024+n]
//        C[m][512+n] = relu(acc+bias[n]) - hist[m*1024+512+n]   (ldc 1024)
// ---------------------------------------------------------------------------
template<int EPI>
__global__ __launch_bounds__(256, 2)
void gemm_split(const uint4* __restrict__ At, const uint4* __restrict__ Bt,
                const float* __restrict__ bias, const float* __restrict__ hist,
                float* __restrict__ C, int Mreal, int row_off, int nblk)
{
    __shared__ uint4 lds[2048];   // A tile [0,1024), B tile [1024,2048)

    const int tid = threadIdx.x;
    // XCD-aware bijective swizzle (m204 general form)
    const int orig = blockIdx.x;
    const int xcd = orig & 7, q = nblk >> 3, rr = nblk & 7;
    const int lid = (xcd < rr ? xcd * (q + 1) : rr * (q + 1) + (xcd - rr) * q) + (orig >> 3);
    const int bm = lid >> 2, bn = lid & 3;

    const int w = tid >> 6, lane = tid & 63;
    const int wm = w >> 1, wn = w & 1;
    const int lg = lane >> 4, lr = lane & 15;
    const int sw = lr & 7;
    const int sbase = w * 256;

    f32x4 acc[4][4];
#pragma unroll
    for (int i = 0; i < 4; ++i)
#pragma unroll
        for (int j = 0; j < 4; ++j) acc[i][j] = {0.f, 0.f, 0.f, 0.f};

    for (int kt = 0; kt < 16; ++kt) {
        const uint4* Atile = At + ((size_t)(bm * 16 + kt)) * 1024;
        const uint4* Btile = Bt + ((size_t)(bn * 16 + kt)) * 1024;
#pragma unroll
        for (int j = 0; j < 4; ++j) {
            const int slot = sbase + j * 64 + lane;
            GLOAD_LDS(Atile + slot, &lds[slot]);
            GLOAD_LDS(Btile + slot, &lds[1024 + slot]);
        }
        __syncthreads();   // drains vmcnt+lgkmcnt (m97 structure)

        bf16x8 ah[4], al[4], bh[4], bl[4];
#pragma unroll
        for (int mi = 0; mi < 4; ++mi) {
            const uint4* rp = &lds[(wm * 64 + mi * 16 + lr) * 8];
            ah[mi] = *(const bf16x8*)&rp[lg ^ sw];
            al[mi] = *(const bf16x8*)&rp[(lg + 4) ^ sw];
        }
#pragma unroll
        for (int ni = 0; ni < 4; ++ni) {
            const uint4* rp = &lds[1024 + (wn * 64 + ni * 16 + lr) * 8];
            bh[ni] = *(const bf16x8*)&rp[lg ^ sw];
            bl[ni] = *(const bf16x8*)&rp[(lg + 4) ^ sw];
        }
#pragma unroll
        for (int mi = 0; mi < 4; ++mi)
#pragma unroll
            for (int ni = 0; ni < 4; ++ni) {
                f32x4 c = acc[mi][ni];
                c = __builtin_amdgcn_mfma_f32_16x16x32_bf16(ah[mi], bh[ni], c, 0, 0, 0);
                c = __builtin_amdgcn_mfma_f32_16x16x32_bf16(ah[mi], bl[ni], c, 0, 0, 0);
                c = __builtin_amdgcn_mfma_f32_16x16x32_bf16(al[mi], bh[ni], c, 0, 0, 0);
                acc[mi][ni] = c;
            }
        __syncthreads();
    }

#pragma unroll
    for (int mi = 0; mi < 4; ++mi)
#pragma unroll
        for (int ni = 0; ni < 4; ++ni) {
            const int col = bn * 128 + wn * 64 + ni * 16 + lr;
            const float bv = bias[col];
#pragma unroll
            for (int r = 0; r < 4; ++r) {
                const int m = row_off + bm * 128 + wm * 64 + mi * 16 + lg * 4 + r;
                if (m < Mreal) {
                    const float v = acc[mi][ni][r] + bv;
                    if (EPI == 0) {
                        C[(size_t)m * 512 + col] = fmaxf(v, 0.f) - hist[(size_t)m * 512 + col];
                    } else {
                        C[(size_t)m * 1024 + col]       = v - hist[(size_t)m * 1024 + col];
                        C[(size_t)m * 1024 + 512 + col] = fmaxf(v, 0.f) - hist[(size_t)m * 1024 + 512 + col];
                    }
                }
            }
        }
}

// ---------------------------------------------------------------------------
// Small GEMM: out[M,64] = A[M,1024] @ B[64,1024]^T + bias  (fp32 classifier)
// ---------------------------------------------------------------------------
__global__ __launch_bounds__(256)
void gemm64(const float* __restrict__ A, const float* __restrict__ B,
            const float* __restrict__ bias, float* __restrict__ C, int M)
{
    const int K = 1024;
    __shared__ float As[32][68];
    __shared__ float Bs[32][68];
    const int tid = threadIdx.x;
    const int tx = tid & 15, ty = tid >> 4;
    const int lrow = tid >> 3;
    const int lk   = (tid & 7) * 4;
    const int bm = blockIdx.x;

    float acc[4][4];
#pragma unroll
    for (int i = 0; i < 4; ++i)
#pragma unroll
        for (int j = 0; j < 4; ++j) acc[i][j] = 0.f;

    int ar0 = bm * 64 + lrow;      if (ar0 > M - 1) ar0 = M - 1;
    int ar1 = bm * 64 + 32 + lrow; if (ar1 > M - 1) ar1 = M - 1;

    for (int kt = 0; kt < K; kt += 32) {
        float4 a0 = *(const float4*)(A + (size_t)ar0 * K + kt + lk);
        float4 a1 = *(const float4*)(A + (size_t)ar1 * K + kt + lk);
        float4 b0 = *(const float4*)(B + (size_t)lrow * K + kt + lk);
        float4 b1 = *(const float4*)(B + (size_t)(32 + lrow) * K + kt + lk);
        __syncthreads();
        As[lk+0][lrow]    = a0.x; As[lk+1][lrow]    = a0.y; As[lk+2][lrow]    = a0.z; As[lk+3][lrow]    = a0.w;
        As[lk+0][lrow+32] = a1.x; As[lk+1][lrow+32] = a1.y; As[lk+2][lrow+32] = a1.z; As[lk+3][lrow+32] = a1.w;
        Bs[lk+0][lrow]    = b0.x; Bs[lk+1][lrow]    = b0.y; Bs[lk+2][lrow]    = b0.z; Bs[lk+3][lrow]    = b0.w;
        Bs[lk+0][lrow+32] = b1.x; Bs[lk+1][lrow+32] = b1.y; Bs[lk+2][lrow+32] = b1.z; Bs[lk+3][lrow+32] = b1.w;
        __syncthreads();
#pragma unroll
        for (int kk = 0; kk < 32; ++kk) {
            float4 av = *(const float4*)&As[kk][ty * 4];
            float4 bv = *(const float4*)&Bs[kk][tx * 4];
            float aa[4] = {av.x, av.y, av.z, av.w};
            float bb[4] = {bv.x, bv.y, bv.z, bv.w};
#pragma unroll
            for (int i = 0; i < 4; ++i)
#pragma unroll
                for (int j = 0; j < 4; ++j)
                    acc[i][j] += aa[i] * bb[j];
        }
    }

    const float4 bv = *(const float4*)&bias[tx * 4];
#pragma unroll
    for (int i = 0; i < 4; ++i) {
        const int m = bm * 64 + ty * 4 + i;
        if (m >= M) continue;
        float4 o;
        o.x = acc[i][0] + bv.x; o.y = acc[i][1] + bv.y;
        o.z = acc[i][2] + bv.z; o.w = acc[i][3] + bv.w;
        *(float4*)&C[(size_t)m * 64 + tx * 4] = o;
    }
}

// ---------------------------------------------------------------------------
// CSR build: degree count -> exclusive scan -> edge scatter
// ---------------------------------------------------------------------------
__global__ void count_deg(const int* __restrict__ dst, int* __restrict__ deg, int E)
{
    int e = blockIdx.x * blockDim.x + threadIdx.x;
    if (e < E) atomicAdd(&deg[dst[e]], 1);
}

__global__ __launch_bounds__(1024)
void exscan(const int* __restrict__ deg, int* __restrict__ off, int* __restrict__ cur, int n)
{
    __shared__ int wsum[16];
    __shared__ int carry;
    const int tid = threadIdx.x, lane = tid & 63, w = tid >> 6;
    if (tid == 0) carry = 0;
    __syncthreads();
    for (int base = 0; base < n; base += 1024) {
        const int i = base + tid;
        const int v = (i < n) ? deg[i] : 0;
        int x = v;
#pragma unroll
        for (int d = 1; d < 64; d <<= 1) {
            int y = __shfl_up(x, d, 64);
            if (lane >= d) x += y;
        }
        if (lane == 63) wsum[w] = x;
        __syncthreads();
        int wo = 0, tot = 0;
#pragma unroll
        for (int k = 0; k < 16; ++k) { int s = wsum[k]; tot += s; if (k < w) wo += s; }
        const int excl = carry + wo + x - v;
        if (i < n) { off[i] = excl; cur[i] = excl; }
        __syncthreads();
        if (tid == 0) carry += tot;
        __syncthreads();
    }
    if (tid == 0) off[n] = carry;
}

__global__ void scatter_edges(const int* __restrict__ src, const int* __restrict__ dst,
                              int* __restrict__ cur, int* __restrict__ eidx, int E)
{
    int e = blockIdx.x * blockDim.x + threadIdx.x;
    if (e < E) {
        int p = atomicAdd(&cur[dst[e]], 1);
        eidx[p] = src[e];
    }
}

// ---------------------------------------------------------------------------
// Segment mean (D=512) + residual add, epilogue writes split-tiled bf16
// planes directly (GEMM2's A). One wave per dst row; lane owns k-octet
// lane*8..lane*8+7 (kt = lane>>2, octet = lane&3). Pad rows write zeros.
// ---------------------------------------------------------------------------
__global__ __launch_bounds__(256)
void seg_mean_split(const float* __restrict__ h, const int* __restrict__ off,
                    const int* __restrict__ eidx, const float* __restrict__ addin,
                    uint4* __restrict__ out, int n_dst, int n_pad)
{
    const int wid = blockIdx.x * 4 + (threadIdx.x >> 6);
    const int lane = threadIdx.x & 63;
    if (wid >= n_pad) return;
    uint4 hi = {0u, 0u, 0u, 0u}, lo = {0u, 0u, 0u, 0u};
    if (wid < n_dst) {
        const int e0 = off[wid], e1 = off[wid + 1];
        float4 a0 = make_float4(0.f, 0.f, 0.f, 0.f);
        float4 a1 = make_float4(0.f, 0.f, 0.f, 0.f);
        for (int e = e0; e < e1; ++e) {
            const float* row = h + (size_t)eidx[e] * 512 + lane * 8;
            float4 v0 = *(const float4*)row;
            float4 v1 = *(const float4*)(row + 4);
            a0.x += v0.x; a0.y += v0.y; a0.z += v0.z; a0.w += v0.w;
            a1.x += v1.x; a1.y += v1.y; a1.z += v1.z; a1.w += v1.w;
        }
        const float s = 1.0f / (float)((e1 - e0) > 0 ? (e1 - e0) : 1);
        const float* ad = addin + (size_t)wid * 512 + lane * 8;
        float4 d0 = *(const float4*)ad;
        float4 d1 = *(const float4*)(ad + 4);
        float4 r0, r1;
        r0.x = a0.x * s + d0.x; r0.y = a0.y * s + d0.y; r0.z = a0.z * s + d0.z; r0.w = a0.w * s + d0.w;
        r1.x = a1.x * s + d1.x; r1.y = a1.y * s + d1.y; r1.z = a1.z * s + d1.z; r1.w = a1.w * s + d1.w;
        split8(r0, r1, hi, lo);
    }
    const int mt = wid >> 7, r = wid & 127;
    const int kt = lane >> 2, ob = lane & 3;
    const size_t base = ((size_t)(mt * 16 + kt)) * 1024 + r * 8;
    const int swz = r & 7;
    out[base + (ob ^ swz)]       = hi;
    out[base + ((ob + 4) ^ swz)] = lo;
}

// ---------------------------------------------------------------------------
// Segment mean + residual add, plain fp32 out (D=1024), for agg1
// ---------------------------------------------------------------------------
__global__ __launch_bounds__(256)
void seg_mean_add4(const float* __restrict__ h, const int* __restrict__ off,
                   const int* __restrict__ eidx, const float* __restrict__ addin,
                   float* __restrict__ out, int n_dst)
{
    const int D = 1024;
    const int wid = blockIdx.x * 4 + (threadIdx.x >> 6);
    const int lane = threadIdx.x & 63;
    if (wid >= n_dst) return;
    const int e0 = off[wid], e1 = off[wid + 1];
    float4 acc[4];
#pragma unroll
    for (int j = 0; j < 4; ++j) acc[j] = make_float4(0.f, 0.f, 0.f, 0.f);
    for (int e = e0; e < e1; ++e) {
        const float4* row = (const float4*)(h + (size_t)eidx[e] * D);
#pragma unroll
        for (int j = 0; j < 4; ++j) {
            float4 v = row[lane + 64 * j];
            acc[j].x += v.x; acc[j].y += v.y; acc[j].z += v.z; acc[j].w += v.w;
        }
    }
    const float s = 1.0f / (float)((e1 - e0) > 0 ? (e1 - e0) : 1);
    const float4* ad = (const float4*)(addin + (size_t)wid * D);
    float4* o = (float4*)(out + (size_t)wid * D);
#pragma unroll
    for (int j = 0; j < 4; ++j) {
        float4 a = ad[lane + 64 * j];
        float4 r;
        r.x = acc[j].x * s + a.x; r.y = acc[j].y * s + a.y;
        r.z = acc[j].z * s + a.z; r.w = acc[j].w * s + a.w;
        o[lane + 64 * j] = r;
    }
}

// ---------------------------------------------------------------------------
extern "C" void kernel_launch(void* const* d_in, const int* in_sizes, int n_in,
                              void* d_out, int out_size, void* d_ws, size_t ws_size,
                              hipStream_t stream)
{
    const float* feats   = (const float*)d_in[0];
    const float* h0_hist = (const float*)d_in[1];
    const float* agg_h0  = (const float*)d_in[2];
    const float* h1_hist = (const float*)d_in[3];
    const float* agg_h1  = (const float*)d_in[4];
    const float* W0 = (const float*)d_in[5];
    const float* b0 = (const float*)d_in[6];
    const float* W1 = (const float*)d_in[7];
    const float* b1 = (const float*)d_in[8];
    const float* W2 = (const float*)d_in[9];
    const float* b2 = (const float*)d_in[10];
    const int* src0 = (const int*)d_in[11];
    const int* dst0 = (const int*)d_in[12];
    const int* src1 = (const int*)d_in[13];
    const int* dst1 = (const int*)d_in[14];

    const int MT1 = 782;                       // ceil(100000/128)
    const int MT2 = 196;                       // ceil(25000/128)
    const size_t TILEB = 16 * 1024 * 16;       // 256 KiB per M-tile (16 kt x 16KB)

    const size_t h0B   = (size_t)N0c * 512 * 4;          // 204.8 MB (h1cat overlays)
    const size_t a2B   = (size_t)MT2 * TILEB;            // 51.4 MB
    const size_t agg1B = (size_t)N2c * 1024 * 4;         // 20.5 MB
    const size_t wsB   = 4 * 16 * 1024 * 16;             // 1 MB per weight split
    const size_t intB  = ((size_t)(N1c + (N1c + 1) + N1c + E0c + N2c + (N2c + 1) + N2c + E1c) * 4 + 15) & ~(size_t)15;
    const size_t FIXED = h0B + a2B + agg1B + 2 * wsB + intB;

    // adaptive chunking of the feats split buffer
    size_t avail = (ws_size > FIXED) ? (ws_size - FIXED) : 0;
    int ct = (int)(avail / TILEB);
    if (ct < 8) ct = 8;
    if (ct > MT1) ct = MT1;
    const int nchunks = (MT1 + ct - 1) / ct;

    char* ws = (char*)d_ws;
    uint4* Achunk = (uint4*)ws;                            ws += (size_t)ct * TILEB;
    float* h0     = (float*)ws;  float* h1cat = h0;        ws += h0B;
    uint4* A2s    = (uint4*)ws;                            ws += a2B;
    float* agg1   = (float*)ws;                            ws += agg1B;
    uint4* Ws0    = (uint4*)ws;                            ws += wsB;
    uint4* Ws1    = (uint4*)ws;                            ws += wsB;
    int* deg0  = (int*)ws;  ws += sizeof(int) * N1c;
    int* off0  = (int*)ws;  ws += sizeof(int) * (N1c + 1);
    int* cur0  = (int*)ws;  ws += sizeof(int) * N1c;
    int* eidx0 = (int*)ws;  ws += sizeof(int) * E0c;
    int* deg1  = (int*)ws;  ws += sizeof(int) * N2c;
    int* off1  = (int*)ws;  ws += sizeof(int) * (N2c + 1);
    int* cur1  = (int*)ws;  ws += sizeof(int) * N2c;
    int* eidx1 = (int*)ws;

    hipMemsetAsync(deg0, 0, sizeof(int) * N1c, stream);
    hipMemsetAsync(deg1, 0, sizeof(int) * N2c, stream);

    // weight splits (tiny) + CSR level 0 (independent of GEMM1)
    presplit<<<4 * 64, 256, 0, stream>>>(W0, Ws0, 512, 0, 4);
    presplit<<<4 * 64, 256, 0, stream>>>(W1, Ws1, 512, 0, 4);
    count_deg<<<(E0c + 255) / 256, 256, 0, stream>>>(dst0, deg0, E0c);
    exscan<<<1, 1024, 0, stream>>>(deg0, off0, cur0, N1c);
    scatter_edges<<<(E0c + 255) / 256, 256, 0, stream>>>(src0, dst0, cur0, eidx0, E0c);

    // layer 0: h0 = relu(feats @ W0^T + b0) - h0_hist   (chunked over M-tiles)
    for (int c = 0; c < nchunks; ++c) {
        const int t0 = c * ct;
        const int nt = (MT1 - t0 < ct) ? (MT1 - t0) : ct;
        presplit<<<nt * 64, 256, 0, stream>>>(feats, Achunk, N0c, t0, nt);
        const int nblk = nt * 4;
        gemm_split<0><<<nblk, 256, 0, stream>>>(Achunk, Ws0, b0, h0_hist, h0, N0c, t0 * 128, nblk);
    }

    // agg0 = segment_mean(h0) + agg_h0, written directly as split-tiled bf16
    seg_mean_split<<<(MT2 * 128) / 4, 256, 0, stream>>>(h0, off0, eidx0, agg_h0, A2s, N1c, MT2 * 128);

    // CSR level 1
    count_deg<<<(E1c + 255) / 256, 256, 0, stream>>>(dst1, deg1, E1c);
    exscan<<<1, 1024, 0, stream>>>(deg1, off1, cur1, N2c);
    scatter_edges<<<(E1c + 255) / 256, 256, 0, stream>>>(src1, dst1, cur1, eidx1, E1c);

    // layer 1: h1cat = [h1 | relu(h1)] - h1_hist, h1 = agg0 @ W1^T + b1
    gemm_split<1><<<MT2 * 4, 256, 0, stream>>>(A2s, Ws1, b1, h1_hist, h1cat, N1c, 0, MT2 * 4);

    // agg1 = segment_mean(h1cat) + agg_h1
    seg_mean_add4<<<(N2c + 3) / 4, 256, 0, stream>>>(h1cat, off1, eidx1, agg_h1, agg1, N2c);

    // classifier: out = agg1 @ W2^T + b2
    gemm64<<<(N2c + 63) / 64, 256, 0, stream>>>(agg1, W2, b2, (float*)d_out, N2c);
}

// Round 5
// 662.258 us; speedup vs baseline: 1.7292x; 1.1718x over previous
//
#include <hip/hip_runtime.h>

#define N0c 100000
#define N1c 25000
#define N2c 5000
#define E0c 400000
#define E1c 80000
// IN_FEATS = N_HIDDEN = 512, N_CLASSES = 64
// M-tiles (128 rows): GEMM1 782, GEMM2 196

typedef __attribute__((ext_vector_type(8))) short bf16x8;
typedef __attribute__((ext_vector_type(4))) float f32x4;

#define GLOAD_LDS(g, l) \
    __builtin_amdgcn_global_load_lds((__attribute__((address_space(1))) const unsigned int*)(const void*)(g), \
                                     (__attribute__((address_space(3))) unsigned int*)(void*)(l), 16, 0, 0)

// round-to-nearest-even bf16, returned as fp32 bit pattern (low 16 zeroed)
static __device__ __forceinline__ uint rnd_bf(float f) {
    uint u = __float_as_uint(f);
    return (u + 0x7FFFu + ((u >> 16) & 1u)) & 0xFFFF0000u;
}
static __device__ __forceinline__ unsigned short to_bf(float f) {
    return (unsigned short)(rnd_bf(f) >> 16);
}
// pack two floats -> one uint holding 2 bf16 (low = f0, high = f1)
static __device__ __forceinline__ uint pk_bf(float f0, float f1) {
    return (rnd_bf(f0) >> 16) | rnd_bf(f1);
}

// ---------------------------------------------------------------------------
// Pre-convert: X[M][512] fp32 -> bf16 tiled planes (layout == GEMM LDS).
// Tile = 128 rows x 64 k bf16 = 16 KiB: [r=128][p=8 x 16B slots],
// physical slot p holds k-octet o = p ^ (r&7)  (k = kt8*64 + o*8).
// Buffer: [mtl*8 + kt8][1024 uint4]. Rows >= M zeroed. Linear writes.
// ---------------------------------------------------------------------------
__global__ __launch_bounds__(256)
void presplit_bf(const float* __restrict__ X, uint4* __restrict__ out,
                 int M, int tile0, int ntiles)
{
    const int id = blockIdx.x * 256 + threadIdx.x;
    const int slot = id & 1023;            // r*8 + p
    const int tk = id >> 10;               // mtl*8 + kt8
    if (tk >= ntiles * 8) return;
    const int kt8 = tk & 7, mtl = tk >> 3;
    const int r = slot >> 3, p = slot & 7;
    const int o = p ^ (r & 7);
    const int row = (tile0 + mtl) * 128 + r;
    uint4 v = {0u, 0u, 0u, 0u};
    if (row < M) {
        const float* src = X + (size_t)row * 512 + kt8 * 64 + o * 8;
        float4 x0 = *(const float4*)src;
        float4 x1 = *(const float4*)(src + 4);
        v.x = pk_bf(x0.x, x0.y); v.y = pk_bf(x0.z, x0.w);
        v.z = pk_bf(x1.x, x1.y); v.w = pk_bf(x1.z, x1.w);
    }
    out[(size_t)tk * 1024 + slot] = v;
}

// ---------------------------------------------------------------------------
// Pure-bf16 MFMA GEMM (NT): C[M,512] = A[M,512] @ B[512,512]^T.
// 128x128 tile, 4 waves (2x2), BK=64 (8 K-steps), counted-vmcnt
// double-buffer: stage = 8 global_load_lds/wave; prologue T0,T1 (16
// outstanding); loop waits vmcnt(8) -> exactly one tile stays in flight.
// EPI 0: Cb[m*512+n]      = bf16(relu(acc+bias)-hist[m*512+n])
// EPI 1: Cb[m*1024+n]     = bf16((acc+bias)-hist[m*1024+n])
//        Cb[m*1024+512+n] = bf16(relu(acc+bias)-hist[m*1024+512+n])
// ---------------------------------------------------------------------------
template<int EPI>
__global__ __launch_bounds__(256, 2)
void gemm_bf16(const uint4* __restrict__ At, const uint4* __restrict__ Bt,
               const float* __restrict__ bias, const float* __restrict__ hist,
               unsigned short* __restrict__ C, int Mreal, int row_off, int nblk)
{
    __shared__ uint4 lds[4096];   // buf b at b*2048: A [0,1024), B [1024,2048)

    const int tid = threadIdx.x;
    // XCD-aware bijective swizzle (m204 general form)
    const int orig = blockIdx.x;
    const int xcd = orig & 7, q = nblk >> 3, rr = nblk & 7;
    const int lid = (xcd < rr ? xcd * (q + 1) : rr * (q + 1) + (xcd - rr) * q) + (orig >> 3);
    const int bm = lid >> 2, bn = lid & 3;

    const int w = tid >> 6, lane = tid & 63;
    const int wm = w >> 1, wn = w & 1;
    const int lg = lane >> 4, lr = lane & 15;
    const int sw = lr & 7;
    const int sbase = w * 256;

    const uint4* Abase = At + (size_t)bm * 8 * 1024;
    const uint4* Bbase = Bt + (size_t)bn * 8 * 1024;

    f32x4 acc[4][4];
#pragma unroll
    for (int i = 0; i < 4; ++i)
#pragma unroll
        for (int j = 0; j < 4; ++j) acc[i][j] = {0.f, 0.f, 0.f, 0.f};

    // prologue: T0 -> buf0 (oldest 8), fence, T1 -> buf1 (next 8)
#pragma unroll
    for (int j = 0; j < 4; ++j) {
        const int slot = sbase + j * 64 + lane;
        GLOAD_LDS(Abase + slot, &lds[slot]);
        GLOAD_LDS(Bbase + slot, &lds[1024 + slot]);
    }
    asm volatile("" ::: "memory");
#pragma unroll
    for (int j = 0; j < 4; ++j) {
        const int slot = sbase + j * 64 + lane;
        GLOAD_LDS(Abase + 1024 + slot, &lds[2048 + slot]);
        GLOAD_LDS(Bbase + 1024 + slot, &lds[3072 + slot]);
    }

    // Outstanding ledger: entry of iter j: {T_j(8), T_{j+1}(8)}.
    // wait vmcnt(8) completes T_j; stage T_{j+2} after barrier2 -> 16 again.
    for (int kt = 0; kt < 7; ++kt) {
        const int cb = (kt & 1) << 11;
        asm volatile("s_waitcnt vmcnt(8)" ::: "memory");
        __builtin_amdgcn_s_barrier();
        asm volatile("" ::: "memory");

        bf16x8 a[4][2], b[4][2];
#pragma unroll
        for (int mi = 0; mi < 4; ++mi) {
            const uint4* rp = &lds[cb + (wm * 64 + mi * 16 + lr) * 8];
            a[mi][0] = *(const bf16x8*)&rp[lg ^ sw];
            a[mi][1] = *(const bf16x8*)&rp[(4 + lg) ^ sw];
        }
#pragma unroll
        for (int ni = 0; ni < 4; ++ni) {
            const uint4* rp = &lds[cb + 1024 + (wn * 64 + ni * 16 + lr) * 8];
            b[ni][0] = *(const bf16x8*)&rp[lg ^ sw];
            b[ni][1] = *(const bf16x8*)&rp[(4 + lg) ^ sw];
        }
        __builtin_amdgcn_s_setprio(1);
#pragma unroll
        for (int kk = 0; kk < 2; ++kk)
#pragma unroll
            for (int mi = 0; mi < 4; ++mi)
#pragma unroll
                for (int ni = 0; ni < 4; ++ni)
                    acc[mi][ni] = __builtin_amdgcn_mfma_f32_16x16x32_bf16(
                        a[mi][kk], b[ni][kk], acc[mi][ni], 0, 0, 0);
        __builtin_amdgcn_s_setprio(0);
        asm volatile("" ::: "memory");
        __builtin_amdgcn_s_barrier();
        asm volatile("" ::: "memory");
        if (kt < 6) {
            const uint4* An = Abase + (size_t)(kt + 2) * 1024;
            const uint4* Bn = Bbase + (size_t)(kt + 2) * 1024;
#pragma unroll
            for (int j = 0; j < 4; ++j) {
                const int slot = sbase + j * 64 + lane;
                GLOAD_LDS(An + slot, &lds[cb + slot]);
                GLOAD_LDS(Bn + slot, &lds[cb + 1024 + slot]);
            }
        }
    }
    // peeled last tile (T7, buf1)
    asm volatile("s_waitcnt vmcnt(0)" ::: "memory");
    __builtin_amdgcn_s_barrier();
    asm volatile("" ::: "memory");
    {
        bf16x8 a[4][2], b[4][2];
#pragma unroll
        for (int mi = 0; mi < 4; ++mi) {
            const uint4* rp = &lds[2048 + (wm * 64 + mi * 16 + lr) * 8];
            a[mi][0] = *(const bf16x8*)&rp[lg ^ sw];
            a[mi][1] = *(const bf16x8*)&rp[(4 + lg) ^ sw];
        }
#pragma unroll
        for (int ni = 0; ni < 4; ++ni) {
            const uint4* rp = &lds[2048 + 1024 + (wn * 64 + ni * 16 + lr) * 8];
            b[ni][0] = *(const bf16x8*)&rp[lg ^ sw];
            b[ni][1] = *(const bf16x8*)&rp[(4 + lg) ^ sw];
        }
#pragma unroll
        for (int kk = 0; kk < 2; ++kk)
#pragma unroll
            for (int mi = 0; mi < 4; ++mi)
#pragma unroll
                for (int ni = 0; ni < 4; ++ni)
                    acc[mi][ni] = __builtin_amdgcn_mfma_f32_16x16x32_bf16(
                        a[mi][kk], b[ni][kk], acc[mi][ni], 0, 0, 0);
    }

    // epilogue: C/D layout col=lane&15, row=(lane>>4)*4+reg  (m89)
#pragma unroll
    for (int mi = 0; mi < 4; ++mi)
#pragma unroll
        for (int ni = 0; ni < 4; ++ni) {
            const int col = bn * 128 + wn * 64 + ni * 16 + lr;
            const float bv = bias[col];
#pragma unroll
            for (int r = 0; r < 4; ++r) {
                const int m = row_off + bm * 128 + wm * 64 + mi * 16 + lg * 4 + r;
                if (m < Mreal) {
                    const float v = acc[mi][ni][r] + bv;
                    if (EPI == 0) {
                        C[(size_t)m * 512 + col] = to_bf(fmaxf(v, 0.f) - hist[(size_t)m * 512 + col]);
                    } else {
                        C[(size_t)m * 1024 + col]       = to_bf(v - hist[(size_t)m * 1024 + col]);
                        C[(size_t)m * 1024 + 512 + col] = to_bf(fmaxf(v, 0.f) - hist[(size_t)m * 1024 + 512 + col]);
                    }
                }
            }
        }
}

// ---------------------------------------------------------------------------
// Small GEMM: out[M,64] = A[M,1024] @ B[64,1024]^T + bias  (fp32 classifier)
// ---------------------------------------------------------------------------
__global__ __launch_bounds__(256)
void gemm64(const float* __restrict__ A, const float* __restrict__ B,
            const float* __restrict__ bias, float* __restrict__ C, int M)
{
    const int K = 1024;
    __shared__ float As[32][68];
    __shared__ float Bs[32][68];
    const int tid = threadIdx.x;
    const int tx = tid & 15, ty = tid >> 4;
    const int lrow = tid >> 3;
    const int lk   = (tid & 7) * 4;
    const int bm = blockIdx.x;

    float acc[4][4];
#pragma unroll
    for (int i = 0; i < 4; ++i)
#pragma unroll
        for (int j = 0; j < 4; ++j) acc[i][j] = 0.f;

    int ar0 = bm * 64 + lrow;      if (ar0 > M - 1) ar0 = M - 1;
    int ar1 = bm * 64 + 32 + lrow; if (ar1 > M - 1) ar1 = M - 1;

    for (int kt = 0; kt < K; kt += 32) {
        float4 a0 = *(const float4*)(A + (size_t)ar0 * K + kt + lk);
        float4 a1 = *(const float4*)(A + (size_t)ar1 * K + kt + lk);
        float4 b0 = *(const float4*)(B + (size_t)lrow * K + kt + lk);
        float4 b1 = *(const float4*)(B + (size_t)(32 + lrow) * K + kt + lk);
        __syncthreads();
        As[lk+0][lrow]    = a0.x; As[lk+1][lrow]    = a0.y; As[lk+2][lrow]    = a0.z; As[lk+3][lrow]    = a0.w;
        As[lk+0][lrow+32] = a1.x; As[lk+1][lrow+32] = a1.y; As[lk+2][lrow+32] = a1.z; As[lk+3][lrow+32] = a1.w;
        Bs[lk+0][lrow]    = b0.x; Bs[lk+1][lrow]    = b0.y; Bs[lk+2][lrow]    = b0.z; Bs[lk+3][lrow]    = b0.w;
        Bs[lk+0][lrow+32] = b1.x; Bs[lk+1][lrow+32] = b1.y; Bs[lk+2][lrow+32] = b1.z; Bs[lk+3][lrow+32] = b1.w;
        __syncthreads();
#pragma unroll
        for (int kk = 0; kk < 32; ++kk) {
            float4 av = *(const float4*)&As[kk][ty * 4];
            float4 bv = *(const float4*)&Bs[kk][tx * 4];
            float aa[4] = {av.x, av.y, av.z, av.w};
            float bb[4] = {bv.x, bv.y, bv.z, bv.w};
#pragma unroll
            for (int i = 0; i < 4; ++i)
#pragma unroll
                for (int j = 0; j < 4; ++j)
                    acc[i][j] += aa[i] * bb[j];
        }
    }

    const float4 bv = *(const float4*)&bias[tx * 4];
#pragma unroll
    for (int i = 0; i < 4; ++i) {
        const int m = bm * 64 + ty * 4 + i;
        if (m >= M) continue;
        float4 o;
        o.x = acc[i][0] + bv.x; o.y = acc[i][1] + bv.y;
        o.z = acc[i][2] + bv.z; o.w = acc[i][3] + bv.w;
        *(float4*)&C[(size_t)m * 64 + tx * 4] = o;
    }
}

// ---------------------------------------------------------------------------
// CSR build: degree count -> exclusive scan -> edge scatter
// ---------------------------------------------------------------------------
__global__ void count_deg(const int* __restrict__ dst, int* __restrict__ deg, int E)
{
    int e = blockIdx.x * blockDim.x + threadIdx.x;
    if (e < E) atomicAdd(&deg[dst[e]], 1);
}

__global__ __launch_bounds__(1024)
void exscan(const int* __restrict__ deg, int* __restrict__ off, int* __restrict__ cur, int n)
{
    __shared__ int wsum[16];
    __shared__ int carry;
    const int tid = threadIdx.x, lane = tid & 63, w = tid >> 6;
    if (tid == 0) carry = 0;
    __syncthreads();
    for (int base = 0; base < n; base += 1024) {
        const int i = base + tid;
        const int v = (i < n) ? deg[i] : 0;
        int x = v;
#pragma unroll
        for (int d = 1; d < 64; d <<= 1) {
            int y = __shfl_up(x, d, 64);
            if (lane >= d) x += y;
        }
        if (lane == 63) wsum[w] = x;
        __syncthreads();
        int wo = 0, tot = 0;
#pragma unroll
        for (int k = 0; k < 16; ++k) { int s = wsum[k]; tot += s; if (k < w) wo += s; }
        const int excl = carry + wo + x - v;
        if (i < n) { off[i] = excl; cur[i] = excl; }
        __syncthreads();
        if (tid == 0) carry += tot;
        __syncthreads();
    }
    if (tid == 0) off[n] = carry;
}

__global__ void scatter_edges(const int* __restrict__ src, const int* __restrict__ dst,
                              int* __restrict__ cur, int* __restrict__ eidx, int E)
{
    int e = blockIdx.x * blockDim.x + threadIdx.x;
    if (e < E) {
        int p = atomicAdd(&cur[dst[e]], 1);
        eidx[p] = src[e];
    }
}

// ---------------------------------------------------------------------------
// Segment mean over bf16 h (D=512) + fp32 residual add; writes bf16 tiled
// planes (GEMM2's A). One wave per dst row; lane owns k = lane*8..lane*8+7.
// ---------------------------------------------------------------------------
__global__ __launch_bounds__(256)
void seg_mean_split(const unsigned short* __restrict__ h, const int* __restrict__ off,
                    const int* __restrict__ eidx, const float* __restrict__ addin,
                    uint4* __restrict__ out, int n_dst, int n_pad)
{
    const int wid = blockIdx.x * 4 + (threadIdx.x >> 6);
    const int lane = threadIdx.x & 63;
    if (wid >= n_pad) return;
    uint4 v = {0u, 0u, 0u, 0u};
    if (wid < n_dst) {
        const int e0 = off[wid], e1 = off[wid + 1];
        float s[8];
#pragma unroll
        for (int i = 0; i < 8; ++i) s[i] = 0.f;
        for (int e = e0; e < e1; ++e) {
            const uint4 vv = *((const uint4*)(h + (size_t)eidx[e] * 512) + lane);
            const uint u[4] = {vv.x, vv.y, vv.z, vv.w};
#pragma unroll
            for (int i = 0; i < 4; ++i) {
                s[2 * i]     += __uint_as_float(u[i] << 16);
                s[2 * i + 1] += __uint_as_float(u[i] & 0xFFFF0000u);
            }
        }
        const float sc = 1.0f / (float)((e1 - e0) > 0 ? (e1 - e0) : 1);
        const float* ad = addin + (size_t)wid * 512 + lane * 8;
        float4 d0 = *(const float4*)ad;
        float4 d1 = *(const float4*)(ad + 4);
        v.x = pk_bf(s[0] * sc + d0.x, s[1] * sc + d0.y);
        v.y = pk_bf(s[2] * sc + d0.z, s[3] * sc + d0.w);
        v.z = pk_bf(s[4] * sc + d1.x, s[5] * sc + d1.y);
        v.w = pk_bf(s[6] * sc + d1.z, s[7] * sc + d1.w);
    }
    // tiled layout: [mt*8 + kt8][r*8 + (o ^ (r&7))], kt8 = lane>>3, o = lane&7
    const int mt = wid >> 7, r = wid & 127;
    const int kt8 = lane >> 3, o = lane & 7;
    out[((size_t)(mt * 8 + kt8)) * 1024 + r * 8 + (o ^ (r & 7))] = v;
}

// ---------------------------------------------------------------------------
// Segment mean over bf16 h (D=1024) + fp32 residual add -> fp32 out (agg1)
// ---------------------------------------------------------------------------
__global__ __launch_bounds__(256)
void seg_mean_add4(const unsigned short* __restrict__ h, const int* __restrict__ off,
                   const int* __restrict__ eidx, const float* __restrict__ addin,
                   float* __restrict__ out, int n_dst)
{
    const int wid = blockIdx.x * 4 + (threadIdx.x >> 6);
    const int lane = threadIdx.x & 63;
    if (wid >= n_dst) return;
    const int e0 = off[wid], e1 = off[wid + 1];
    float s[16];
#pragma unroll
    for (int i = 0; i < 16; ++i) s[i] = 0.f;
    for (int e = e0; e < e1; ++e) {
        const uint4* row = (const uint4*)(h + (size_t)eidx[e] * 1024);
#pragma unroll
        for (int half = 0; half < 2; ++half) {
            const uint4 v = row[lane + 64 * half];
            const uint u[4] = {v.x, v.y, v.z, v.w};
#pragma unroll
            for (int i = 0; i < 4; ++i) {
                s[8 * half + 2 * i]     += __uint_as_float(u[i] << 16);
                s[8 * half + 2 * i + 1] += __uint_as_float(u[i] & 0xFFFF0000u);
            }
        }
    }
    const float sc = 1.0f / (float)((e1 - e0) > 0 ? (e1 - e0) : 1);
#pragma unroll
    for (int half = 0; half < 2; ++half) {
        const float* ad = addin + (size_t)wid * 1024 + half * 512 + lane * 8;
        float* o = out + (size_t)wid * 1024 + half * 512 + lane * 8;
        float4 d0 = *(const float4*)ad;
        float4 d1 = *(const float4*)(ad + 4);
        float4 r0, r1;
        r0.x = s[8*half+0] * sc + d0.x; r0.y = s[8*half+1] * sc + d0.y;
        r0.z = s[8*half+2] * sc + d0.z; r0.w = s[8*half+3] * sc + d0.w;
        r1.x = s[8*half+4] * sc + d1.x; r1.y = s[8*half+5] * sc + d1.y;
        r1.z = s[8*half+6] * sc + d1.z; r1.w = s[8*half+7] * sc + d1.w;
        *(float4*)o = r0;
        *(float4*)(o + 4) = r1;
    }
}

// ---------------------------------------------------------------------------
extern "C" void kernel_launch(void* const* d_in, const int* in_sizes, int n_in,
                              void* d_out, int out_size, void* d_ws, size_t ws_size,
                              hipStream_t stream)
{
    const float* feats   = (const float*)d_in[0];
    const float* h0_hist = (const float*)d_in[1];
    const float* agg_h0  = (const float*)d_in[2];
    const float* h1_hist = (const float*)d_in[3];
    const float* agg_h1  = (const float*)d_in[4];
    const float* W0 = (const float*)d_in[5];
    const float* b0 = (const float*)d_in[6];
    const float* W1 = (const float*)d_in[7];
    const float* b1 = (const float*)d_in[8];
    const float* W2 = (const float*)d_in[9];
    const float* b2 = (const float*)d_in[10];
    const int* src0 = (const int*)d_in[11];
    const int* dst0 = (const int*)d_in[12];
    const int* src1 = (const int*)d_in[13];
    const int* dst1 = (const int*)d_in[14];

    const int MT1 = 782;                       // ceil(100000/128)
    const int MT2 = 196;                       // ceil(25000/128)
    const size_t TILEB = 8 * 1024 * 16;        // 128 KiB per M-tile (8 kt x 16KB)

    const size_t h0B   = ((size_t)N0c * 512 * 2 + 255) & ~(size_t)255;   // bf16 h0 (h1cat overlays)
    const size_t a2B   = (size_t)MT2 * TILEB;                            // 25.7 MB
    const size_t agg1B = (size_t)N2c * 1024 * 4;                         // 20.5 MB
    const size_t wsB   = 4 * 8 * 1024 * 16;                              // 512 KB per weight plane
    const size_t intB  = ((size_t)(N1c + (N1c + 1) + N1c + E0c + N2c + (N2c + 1) + N2c + E1c) * 4 + 255) & ~(size_t)255;
    const size_t FIXED = h0B + a2B + agg1B + 2 * wsB + intB;             // ~152 MB

    size_t avail = (ws_size > FIXED) ? (ws_size - FIXED) : 0;
    int ct = (int)(avail / TILEB);
    if (ct < 8) ct = 8;
    if (ct > MT1) ct = MT1;
    const int nchunks = (MT1 + ct - 1) / ct;

    char* ws = (char*)d_ws;
    uint4* Achunk = (uint4*)ws;                              ws += (size_t)ct * TILEB;
    unsigned short* h0 = (unsigned short*)ws;
    unsigned short* h1cat = h0;                              ws += h0B;
    uint4* A2s    = (uint4*)ws;                              ws += a2B;
    float* agg1   = (float*)ws;                              ws += agg1B;
    uint4* Ws0    = (uint4*)ws;                              ws += wsB;
    uint4* Ws1    = (uint4*)ws;                              ws += wsB;
    int* deg0  = (int*)ws;  ws += sizeof(int) * N1c;
    int* off0  = (int*)ws;  ws += sizeof(int) * (N1c + 1);
    int* cur0  = (int*)ws;  ws += sizeof(int) * N1c;
    int* eidx0 = (int*)ws;  ws += sizeof(int) * E0c;
    int* deg1  = (int*)ws;  ws += sizeof(int) * N2c;
    int* off1  = (int*)ws;  ws += sizeof(int) * (N2c + 1);
    int* cur1  = (int*)ws;  ws += sizeof(int) * N2c;
    int* eidx1 = (int*)ws;

    hipMemsetAsync(deg0, 0, sizeof(int) * N1c, stream);
    hipMemsetAsync(deg1, 0, sizeof(int) * N2c, stream);

    // weight planes + CSR level 0 (independent of GEMM1)
    presplit_bf<<<4 * 32, 256, 0, stream>>>(W0, Ws0, 512, 0, 4);
    presplit_bf<<<4 * 32, 256, 0, stream>>>(W1, Ws1, 512, 0, 4);
    count_deg<<<(E0c + 255) / 256, 256, 0, stream>>>(dst0, deg0, E0c);
    exscan<<<1, 1024, 0, stream>>>(deg0, off0, cur0, N1c);
    scatter_edges<<<(E0c + 255) / 256, 256, 0, stream>>>(src0, dst0, cur0, eidx0, E0c);

    // layer 0: h0 = bf16(relu(feats @ W0^T + b0) - h0_hist)
    for (int c = 0; c < nchunks; ++c) {
        const int t0 = c * ct;
        const int nt = (MT1 - t0 < ct) ? (MT1 - t0) : ct;
        presplit_bf<<<nt * 32, 256, 0, stream>>>(feats, Achunk, N0c, t0, nt);
        const int nblk = nt * 4;
        gemm_bf16<0><<<nblk, 256, 0, stream>>>(Achunk, Ws0, b0, h0_hist, h0, N0c, t0 * 128, nblk);
    }

    // agg0 = segment_mean(h0) + agg_h0, written as bf16 tiled planes
    seg_mean_split<<<(MT2 * 128) / 4, 256, 0, stream>>>(h0, off0, eidx0, agg_h0, A2s, N1c, MT2 * 128);

    // CSR level 1
    count_deg<<<(E1c + 255) / 256, 256, 0, stream>>>(dst1, deg1, E1c);
    exscan<<<1, 1024, 0, stream>>>(deg1, off1, cur1, N2c);
    scatter_edges<<<(E1c + 255) / 256, 256, 0, stream>>>(src1, dst1, cur1, eidx1, E1c);

    // layer 1: h1cat = bf16([h1 | relu(h1)] - h1_hist), h1 = agg0 @ W1^T + b1
    gemm_bf16<1><<<MT2 * 4, 256, 0, stream>>>(A2s, Ws1, b1, h1_hist, h1cat, N1c, 0, MT2 * 4);

    // agg1 = segment_mean(h1cat) + agg_h1  (fp32)
    seg_mean_add4<<<(N2c + 3) / 4, 256, 0, stream>>>(h1cat, off1, eidx1, agg_h1, agg1, N2c);

    // classifier: out = agg1 @ W2^T + b2
    gemm64<<<(N2c + 63) / 64, 256, 0, stream>>>(agg1, W2, b2, (float*)d_out, N2c);
}

// Round 6
// 592.068 us; speedup vs baseline: 1.9342x; 1.1186x over previous
//
#include <hip/hip_runtime.h>

#define N0c 100000
#define N1c 25000
#define N2c 5000
#define E0c 400000
#define E1c 80000
// IN_FEATS = N_HIDDEN = 512, N_CLASSES = 64
// M-tiles (128 rows): GEMM1 782, GEMM2 196

typedef __attribute__((ext_vector_type(8))) short bf16x8;
typedef __attribute__((ext_vector_type(4))) float f32x4;

#define GLOAD_LDS(g, l) \
    __builtin_amdgcn_global_load_lds((__attribute__((address_space(1))) const unsigned int*)(const void*)(g), \
                                     (__attribute__((address_space(3))) unsigned int*)(void*)(l), 16, 0, 0)

// round-to-nearest-even bf16, returned as fp32 bit pattern (low 16 zeroed)
static __device__ __forceinline__ uint rnd_bf(float f) {
    uint u = __float_as_uint(f);
    return (u + 0x7FFFu + ((u >> 16) & 1u)) & 0xFFFF0000u;
}
static __device__ __forceinline__ unsigned short to_bf(float f) {
    return (unsigned short)(rnd_bf(f) >> 16);
}
// pack two floats -> one uint holding 2 bf16 (low = f0, high = f1)
static __device__ __forceinline__ uint pk_bf(float f0, float f1) {
    return (rnd_bf(f0) >> 16) | rnd_bf(f1);
}

// ---------------------------------------------------------------------------
// Pre-convert: X[M][512] fp32 -> bf16 tiled planes (layout == GEMM LDS).
// Tile = 128 rows x 64 k bf16 = 16 KiB: [r=128][p=8 x 16B slots],
// physical slot p holds k-octet o = p ^ (r&7)  (k = kt8*64 + o*8).
// Buffer: [mtl*8 + kt8][1024 uint4]. Rows >= M zeroed. Linear writes.
// ---------------------------------------------------------------------------
__global__ __launch_bounds__(256)
void presplit_bf(const float* __restrict__ X, uint4* __restrict__ out,
                 int M, int tile0, int ntiles)
{
    const int id = blockIdx.x * 256 + threadIdx.x;
    const int slot = id & 1023;            // r*8 + p
    const int tk = id >> 10;               // mtl*8 + kt8
    if (tk >= ntiles * 8) return;
    const int kt8 = tk & 7, mtl = tk >> 3;
    const int r = slot >> 3, p = slot & 7;
    const int o = p ^ (r & 7);
    const int row = (tile0 + mtl) * 128 + r;
    uint4 v = {0u, 0u, 0u, 0u};
    if (row < M) {
        const float* src = X + (size_t)row * 512 + kt8 * 64 + o * 8;
        float4 x0 = *(const float4*)src;
        float4 x1 = *(const float4*)(src + 4);
        v.x = pk_bf(x0.x, x0.y); v.y = pk_bf(x0.z, x0.w);
        v.z = pk_bf(x1.x, x1.y); v.w = pk_bf(x1.z, x1.w);
    }
    out[(size_t)tk * 1024 + slot] = v;
}

// ---------------------------------------------------------------------------
// Pure-bf16 MFMA GEMM (NT): C[M,512] = A[M,512] @ B[512,512]^T.
// m97 structure: 128x128 tile, 4 waves (2x2), BK=64, SINGLE 32-KB LDS
// buffer, 2 barriers per K-step (compiler drains vmcnt at __syncthreads),
// latency hidden by ~3 blocks/CU TLP. No setprio, no manual vmcnt.
// EPI 0: Cb[m*512+n]      = bf16(relu(acc+bias)-hist[m*512+n])
// EPI 1: Cb[m*1024+n]     = bf16((acc+bias)-hist[m*1024+n])
//        Cb[m*1024+512+n] = bf16(relu(acc+bias)-hist[m*1024+512+n])
// ---------------------------------------------------------------------------
template<int EPI>
__global__ __launch_bounds__(256, 2)
void gemm_bf16(const uint4* __restrict__ At, const uint4* __restrict__ Bt,
               const float* __restrict__ bias, const float* __restrict__ hist,
               unsigned short* __restrict__ C, int Mreal, int row_off, int nblk)
{
    __shared__ uint4 lds[2048];   // A [0,1024), B [1024,2048)

    const int tid = threadIdx.x;
    // XCD-aware bijective swizzle (m204 general form)
    const int orig = blockIdx.x;
    const int xcd = orig & 7, q = nblk >> 3, rr = nblk & 7;
    const int lid = (xcd < rr ? xcd * (q + 1) : rr * (q + 1) + (xcd - rr) * q) + (orig >> 3);
    const int bm = lid >> 2, bn = lid & 3;

    const int w = tid >> 6, lane = tid & 63;
    const int wm = w >> 1, wn = w & 1;
    const int lg = lane >> 4, lr = lane & 15;
    const int sw = lr & 7;
    const int sbase = w * 256;

    const uint4* Abase = At + (size_t)bm * 8 * 1024;
    const uint4* Bbase = Bt + (size_t)bn * 8 * 1024;

    f32x4 acc[4][4];
#pragma unroll
    for (int i = 0; i < 4; ++i)
#pragma unroll
        for (int j = 0; j < 4; ++j) acc[i][j] = {0.f, 0.f, 0.f, 0.f};

    for (int kt = 0; kt < 8; ++kt) {
        if (kt) __syncthreads();          // all waves done reading buffer
        const uint4* Atile = Abase + (size_t)kt * 1024;
        const uint4* Btile = Bbase + (size_t)kt * 1024;
#pragma unroll
        for (int j = 0; j < 4; ++j) {
            const int slot = sbase + j * 64 + lane;
            GLOAD_LDS(Atile + slot, &lds[slot]);
            GLOAD_LDS(Btile + slot, &lds[1024 + slot]);
        }
        __syncthreads();                  // compiler drains vmcnt+lgkm here

        bf16x8 a[4][2], b[4][2];
#pragma unroll
        for (int mi = 0; mi < 4; ++mi) {
            const uint4* rp = &lds[(wm * 64 + mi * 16 + lr) * 8];
            a[mi][0] = *(const bf16x8*)&rp[lg ^ sw];
            a[mi][1] = *(const bf16x8*)&rp[(4 + lg) ^ sw];
        }
#pragma unroll
        for (int ni = 0; ni < 4; ++ni) {
            const uint4* rp = &lds[1024 + (wn * 64 + ni * 16 + lr) * 8];
            b[ni][0] = *(const bf16x8*)&rp[lg ^ sw];
            b[ni][1] = *(const bf16x8*)&rp[(4 + lg) ^ sw];
        }
#pragma unroll
        for (int kk = 0; kk < 2; ++kk)
#pragma unroll
            for (int mi = 0; mi < 4; ++mi)
#pragma unroll
                for (int ni = 0; ni < 4; ++ni)
                    acc[mi][ni] = __builtin_amdgcn_mfma_f32_16x16x32_bf16(
                        a[mi][kk], b[ni][kk], acc[mi][ni], 0, 0, 0);
    }

    // epilogue: C/D layout col=lane&15, row=(lane>>4)*4+reg  (m89)
#pragma unroll
    for (int mi = 0; mi < 4; ++mi)
#pragma unroll
        for (int ni = 0; ni < 4; ++ni) {
            const int col = bn * 128 + wn * 64 + ni * 16 + lr;
            const float bv = bias[col];
#pragma unroll
            for (int r = 0; r < 4; ++r) {
                const int m = row_off + bm * 128 + wm * 64 + mi * 16 + lg * 4 + r;
                if (m < Mreal) {
                    const float v = acc[mi][ni][r] + bv;
                    if (EPI == 0) {
                        C[(size_t)m * 512 + col] = to_bf(fmaxf(v, 0.f) - hist[(size_t)m * 512 + col]);
                    } else {
                        C[(size_t)m * 1024 + col]       = to_bf(v - hist[(size_t)m * 1024 + col]);
                        C[(size_t)m * 1024 + 512 + col] = to_bf(fmaxf(v, 0.f) - hist[(size_t)m * 1024 + 512 + col]);
                    }
                }
            }
        }
}

// ---------------------------------------------------------------------------
// Small GEMM: out[M,64] = A[M,1024] @ B[64,1024]^T + bias  (fp32 classifier)
// ---------------------------------------------------------------------------
__global__ __launch_bounds__(256)
void gemm64(const float* __restrict__ A, const float* __restrict__ B,
            const float* __restrict__ bias, float* __restrict__ C, int M)
{
    const int K = 1024;
    __shared__ float As[32][68];
    __shared__ float Bs[32][68];
    const int tid = threadIdx.x;
    const int tx = tid & 15, ty = tid >> 4;
    const int lrow = tid >> 3;
    const int lk   = (tid & 7) * 4;
    const int bm = blockIdx.x;

    float acc[4][4];
#pragma unroll
    for (int i = 0; i < 4; ++i)
#pragma unroll
        for (int j = 0; j < 4; ++j) acc[i][j] = 0.f;

    int ar0 = bm * 64 + lrow;      if (ar0 > M - 1) ar0 = M - 1;
    int ar1 = bm * 64 + 32 + lrow; if (ar1 > M - 1) ar1 = M - 1;

    for (int kt = 0; kt < K; kt += 32) {
        float4 a0 = *(const float4*)(A + (size_t)ar0 * K + kt + lk);
        float4 a1 = *(const float4*)(A + (size_t)ar1 * K + kt + lk);
        float4 b0 = *(const float4*)(B + (size_t)lrow * K + kt + lk);
        float4 b1 = *(const float4*)(B + (size_t)(32 + lrow) * K + kt + lk);
        __syncthreads();
        As[lk+0][lrow]    = a0.x; As[lk+1][lrow]    = a0.y; As[lk+2][lrow]    = a0.z; As[lk+3][lrow]    = a0.w;
        As[lk+0][lrow+32] = a1.x; As[lk+1][lrow+32] = a1.y; As[lk+2][lrow+32] = a1.z; As[lk+3][lrow+32] = a1.w;
        Bs[lk+0][lrow]    = b0.x; Bs[lk+1][lrow]    = b0.y; Bs[lk+2][lrow]    = b0.z; Bs[lk+3][lrow]    = b0.w;
        Bs[lk+0][lrow+32] = b1.x; Bs[lk+1][lrow+32] = b1.y; Bs[lk+2][lrow+32] = b1.z; Bs[lk+3][lrow+32] = b1.w;
        __syncthreads();
#pragma unroll
        for (int kk = 0; kk < 32; ++kk) {
            float4 av = *(const float4*)&As[kk][ty * 4];
            float4 bv = *(const float4*)&Bs[kk][tx * 4];
            float aa[4] = {av.x, av.y, av.z, av.w};
            float bb[4] = {bv.x, bv.y, bv.z, bv.w};
#pragma unroll
            for (int i = 0; i < 4; ++i)
#pragma unroll
                for (int j = 0; j < 4; ++j)
                    acc[i][j] += aa[i] * bb[j];
        }
    }

    const float4 bv = *(const float4*)&bias[tx * 4];
#pragma unroll
    for (int i = 0; i < 4; ++i) {
        const int m = bm * 64 + ty * 4 + i;
        if (m >= M) continue;
        float4 o;
        o.x = acc[i][0] + bv.x; o.y = acc[i][1] + bv.y;
        o.z = acc[i][2] + bv.z; o.w = acc[i][3] + bv.w;
        *(float4*)&C[(size_t)m * 64 + tx * 4] = o;
    }
}

// ---------------------------------------------------------------------------
// CSR build: degree count -> exclusive scan -> edge scatter
// ---------------------------------------------------------------------------
__global__ void count_deg(const int* __restrict__ dst, int* __restrict__ deg, int E)
{
    int e = blockIdx.x * blockDim.x + threadIdx.x;
    if (e < E) atomicAdd(&deg[dst[e]], 1);
}

__global__ __launch_bounds__(1024)
void exscan(const int* __restrict__ deg, int* __restrict__ off, int* __restrict__ cur, int n)
{
    __shared__ int wsum[16];
    __shared__ int carry;
    const int tid = threadIdx.x, lane = tid & 63, w = tid >> 6;
    if (tid == 0) carry = 0;
    __syncthreads();
    for (int base = 0; base < n; base += 1024) {
        const int i = base + tid;
        const int v = (i < n) ? deg[i] : 0;
        int x = v;
#pragma unroll
        for (int d = 1; d < 64; d <<= 1) {
            int y = __shfl_up(x, d, 64);
            if (lane >= d) x += y;
        }
        if (lane == 63) wsum[w] = x;
        __syncthreads();
        int wo = 0, tot = 0;
#pragma unroll
        for (int k = 0; k < 16; ++k) { int s = wsum[k]; tot += s; if (k < w) wo += s; }
        const int excl = carry + wo + x - v;
        if (i < n) { off[i] = excl; cur[i] = excl; }
        __syncthreads();
        if (tid == 0) carry += tot;
        __syncthreads();
    }
    if (tid == 0) off[n] = carry;
}

__global__ void scatter_edges(const int* __restrict__ src, const int* __restrict__ dst,
                              int* __restrict__ cur, int* __restrict__ eidx, int E)
{
    int e = blockIdx.x * blockDim.x + threadIdx.x;
    if (e < E) {
        int p = atomicAdd(&cur[dst[e]], 1);
        eidx[p] = src[e];
    }
}

// ---------------------------------------------------------------------------
// Segment mean over bf16 h (D=512) + fp32 residual add; writes bf16 tiled
// planes (GEMM2's A). One wave per dst row; lane owns k = lane*8..lane*8+7.
// ---------------------------------------------------------------------------
__global__ __launch_bounds__(256)
void seg_mean_split(const unsigned short* __restrict__ h, const int* __restrict__ off,
                    const int* __restrict__ eidx, const float* __restrict__ addin,
                    uint4* __restrict__ out, int n_dst, int n_pad)
{
    const int wid = blockIdx.x * 4 + (threadIdx.x >> 6);
    const int lane = threadIdx.x & 63;
    if (wid >= n_pad) return;
    uint4 v = {0u, 0u, 0u, 0u};
    if (wid < n_dst) {
        const int e0 = off[wid], e1 = off[wid + 1];
        float s[8];
#pragma unroll
        for (int i = 0; i < 8; ++i) s[i] = 0.f;
        for (int e = e0; e < e1; ++e) {
            const uint4 vv = *((const uint4*)(h + (size_t)eidx[e] * 512) + lane);
            const uint u[4] = {vv.x, vv.y, vv.z, vv.w};
#pragma unroll
            for (int i = 0; i < 4; ++i) {
                s[2 * i]     += __uint_as_float(u[i] << 16);
                s[2 * i + 1] += __uint_as_float(u[i] & 0xFFFF0000u);
            }
        }
        const float sc = 1.0f / (float)((e1 - e0) > 0 ? (e1 - e0) : 1);
        const float* ad = addin + (size_t)wid * 512 + lane * 8;
        float4 d0 = *(const float4*)ad;
        float4 d1 = *(const float4*)(ad + 4);
        v.x = pk_bf(s[0] * sc + d0.x, s[1] * sc + d0.y);
        v.y = pk_bf(s[2] * sc + d0.z, s[3] * sc + d0.w);
        v.z = pk_bf(s[4] * sc + d1.x, s[5] * sc + d1.y);
        v.w = pk_bf(s[6] * sc + d1.z, s[7] * sc + d1.w);
    }
    // tiled layout: [mt*8 + kt8][r*8 + (o ^ (r&7))], kt8 = lane>>3, o = lane&7
    const int mt = wid >> 7, r = wid & 127;
    const int kt8 = lane >> 3, o = lane & 7;
    out[((size_t)(mt * 8 + kt8)) * 1024 + r * 8 + (o ^ (r & 7))] = v;
}

// ---------------------------------------------------------------------------
// Segment mean over bf16 h (D=1024) + fp32 residual add -> fp32 out (agg1)
// ---------------------------------------------------------------------------
__global__ __launch_bounds__(256)
void seg_mean_add4(const unsigned short* __restrict__ h, const int* __restrict__ off,
                   const int* __restrict__ eidx, const float* __restrict__ addin,
                   float* __restrict__ out, int n_dst)
{
    const int wid = blockIdx.x * 4 + (threadIdx.x >> 6);
    const int lane = threadIdx.x & 63;
    if (wid >= n_dst) return;
    const int e0 = off[wid], e1 = off[wid + 1];
    float s[16];
#pragma unroll
    for (int i = 0; i < 16; ++i) s[i] = 0.f;
    for (int e = e0; e < e1; ++e) {
        const uint4* row = (const uint4*)(h + (size_t)eidx[e] * 1024);
#pragma unroll
        for (int half = 0; half < 2; ++half) {
            const uint4 v = row[lane + 64 * half];
            const uint u[4] = {v.x, v.y, v.z, v.w};
#pragma unroll
            for (int i = 0; i < 4; ++i) {
                s[8 * half + 2 * i]     += __uint_as_float(u[i] << 16);
                s[8 * half + 2 * i + 1] += __uint_as_float(u[i] & 0xFFFF0000u);
            }
        }
    }
    const float sc = 1.0f / (float)((e1 - e0) > 0 ? (e1 - e0) : 1);
#pragma unroll
    for (int half = 0; half < 2; ++half) {
        const float* ad = addin + (size_t)wid * 1024 + half * 512 + lane * 8;
        float* o = out + (size_t)wid * 1024 + half * 512 + lane * 8;
        float4 d0 = *(const float4*)ad;
        float4 d1 = *(const float4*)(ad + 4);
        float4 r0, r1;
        r0.x = s[8*half+0] * sc + d0.x; r0.y = s[8*half+1] * sc + d0.y;
        r0.z = s[8*half+2] * sc + d0.z; r0.w = s[8*half+3] * sc + d0.w;
        r1.x = s[8*half+4] * sc + d1.x; r1.y = s[8*half+5] * sc + d1.y;
        r1.z = s[8*half+6] * sc + d1.z; r1.w = s[8*half+7] * sc + d1.w;
        *(float4*)o = r0;
        *(float4*)(o + 4) = r1;
    }
}

// ---------------------------------------------------------------------------
extern "C" void kernel_launch(void* const* d_in, const int* in_sizes, int n_in,
                              void* d_out, int out_size, void* d_ws, size_t ws_size,
                              hipStream_t stream)
{
    const float* feats   = (const float*)d_in[0];
    const float* h0_hist = (const float*)d_in[1];
    const float* agg_h0  = (const float*)d_in[2];
    const float* h1_hist = (const float*)d_in[3];
    const float* agg_h1  = (const float*)d_in[4];
    const float* W0 = (const float*)d_in[5];
    const float* b0 = (const float*)d_in[6];
    const float* W1 = (const float*)d_in[7];
    const float* b1 = (const float*)d_in[8];
    const float* W2 = (const float*)d_in[9];
    const float* b2 = (const float*)d_in[10];
    const int* src0 = (const int*)d_in[11];
    const int* dst0 = (const int*)d_in[12];
    const int* src1 = (const int*)d_in[13];
    const int* dst1 = (const int*)d_in[14];

    const int MT1 = 782;                       // ceil(100000/128)
    const int MT2 = 196;                       // ceil(25000/128)
    const size_t TILEB = 8 * 1024 * 16;        // 128 KiB per M-tile (8 kt x 16KB)

    const size_t h0B   = ((size_t)N0c * 512 * 2 + 255) & ~(size_t)255;   // bf16 h0 (h1cat overlays)
    const size_t a2B   = (size_t)MT2 * TILEB;                            // 25.7 MB
    const size_t agg1B = (size_t)N2c * 1024 * 4;                         // 20.5 MB
    const size_t wsB   = 4 * 8 * 1024 * 16;                              // 512 KB per weight plane
    const size_t intB  = ((size_t)(N1c + (N1c + 1) + N1c + E0c + N2c + (N2c + 1) + N2c + E1c) * 4 + 255) & ~(size_t)255;
    const size_t FIXED = h0B + a2B + agg1B + 2 * wsB + intB;             // ~152 MB

    size_t avail = (ws_size > FIXED) ? (ws_size - FIXED) : 0;
    int ct = (int)(avail / TILEB);
    if (ct < 8) ct = 8;
    if (ct > MT1) ct = MT1;
    const int nchunks = (MT1 + ct - 1) / ct;

    char* ws = (char*)d_ws;
    uint4* Achunk = (uint4*)ws;                              ws += (size_t)ct * TILEB;
    unsigned short* h0 = (unsigned short*)ws;
    unsigned short* h1cat = h0;                              ws += h0B;
    uint4* A2s    = (uint4*)ws;                              ws += a2B;
    float* agg1   = (float*)ws;                              ws += agg1B;
    uint4* Ws0    = (uint4*)ws;                              ws += wsB;
    uint4* Ws1    = (uint4*)ws;                              ws += wsB;
    int* deg0  = (int*)ws;  ws += sizeof(int) * N1c;
    int* off0  = (int*)ws;  ws += sizeof(int) * (N1c + 1);
    int* cur0  = (int*)ws;  ws += sizeof(int) * N1c;
    int* eidx0 = (int*)ws;  ws += sizeof(int) * E0c;
    int* deg1  = (int*)ws;  ws += sizeof(int) * N2c;
    int* off1  = (int*)ws;  ws += sizeof(int) * (N2c + 1);
    int* cur1  = (int*)ws;  ws += sizeof(int) * N2c;
    int* eidx1 = (int*)ws;

    hipMemsetAsync(deg0, 0, sizeof(int) * N1c, stream);
    hipMemsetAsync(deg1, 0, sizeof(int) * N2c, stream);

    // weight planes + CSR level 0 (independent of GEMM1)
    presplit_bf<<<4 * 32, 256, 0, stream>>>(W0, Ws0, 512, 0, 4);
    presplit_bf<<<4 * 32, 256, 0, stream>>>(W1, Ws1, 512, 0, 4);
    count_deg<<<(E0c + 255) / 256, 256, 0, stream>>>(dst0, deg0, E0c);
    exscan<<<1, 1024, 0, stream>>>(deg0, off0, cur0, N1c);
    scatter_edges<<<(E0c + 255) / 256, 256, 0, stream>>>(src0, dst0, cur0, eidx0, E0c);

    // layer 0: h0 = bf16(relu(feats @ W0^T + b0) - h0_hist)
    for (int c = 0; c < nchunks; ++c) {
        const int t0 = c * ct;
        const int nt = (MT1 - t0 < ct) ? (MT1 - t0) : ct;
        presplit_bf<<<nt * 32, 256, 0, stream>>>(feats, Achunk, N0c, t0, nt);
        const int nblk = nt * 4;
        gemm_bf16<0><<<nblk, 256, 0, stream>>>(Achunk, Ws0, b0, h0_hist, h0, N0c, t0 * 128, nblk);
    }

    // agg0 = segment_mean(h0) + agg_h0, written as bf16 tiled planes
    seg_mean_split<<<(MT2 * 128) / 4, 256, 0, stream>>>(h0, off0, eidx0, agg_h0, A2s, N1c, MT2 * 128);

    // CSR level 1
    count_deg<<<(E1c + 255) / 256, 256, 0, stream>>>(dst1, deg1, E1c);
    exscan<<<1, 1024, 0, stream>>>(deg1, off1, cur1, N2c);
    scatter_edges<<<(E1c + 255) / 256, 256, 0, stream>>>(src1, dst1, cur1, eidx1, E1c);

    // layer 1: h1cat = bf16([h1 | relu(h1)] - h1_hist), h1 = agg0 @ W1^T + b1
    gemm_bf16<1><<<MT2 * 4, 256, 0, stream>>>(A2s, Ws1, b1, h1_hist, h1cat, N1c, 0, MT2 * 4);

    // agg1 = segment_mean(h1cat) + agg_h1  (fp32)
    seg_mean_add4<<<(N2c + 3) / 4, 256, 0, stream>>>(h1cat, off1, eidx1, agg_h1, agg1, N2c);

    // classifier: out = agg1 @ W2^T + b2
    gemm64<<<(N2c + 63) / 64, 256, 0, stream>>>(agg1, W2, b2, (float*)d_out, N2c);
}